// Round 12
// baseline (154.823 us; speedup 1.0000x reference)
//
#include <hip/hip_runtime.h>
#include <cmath>

constexpr int IN_F  = 256;

typedef short bf16x8 __attribute__((ext_vector_type(8)));
typedef short short4v __attribute__((ext_vector_type(4)));
typedef float f32x4 __attribute__((ext_vector_type(4)));

__device__ __forceinline__ short f2bf(float f) {
    unsigned u = __float_as_uint(f);
    unsigned r = (u + 0x7FFFu + ((u >> 16) & 1)) >> 16;  // RNE
    return (short)r;
}
__device__ __forceinline__ float b2f(short s) {
    return __uint_as_float(((unsigned)(unsigned short)s) << 16);
}

// ======== XCD-chunked block swizzle (T1) ========
__device__ __forceinline__ int xcd_logical_id()
{
    int nx = gridDim.x, ny = gridDim.y, nz = gridDim.z;
    int flat = blockIdx.x + nx * (blockIdx.y + ny * blockIdx.z);
    int nwg = nx * ny * nz;
    if (nwg & 7) return flat;
    int chunk = nwg >> 3;
    return (flat & 7) * chunk + (flat >> 3);
}

// ======== weight transpose to bf16 (device helper; 32x32 tile) ========
__device__ __forceinline__ void cvt_t_body(
    const float* __restrict__ W, short* __restrict__ Wt, int K, int N,
    int ldwt, int koff, int bk, int bn, int tx, int ty)
{
    __shared__ float tile[32][33];
    for (int i = ty; i < 32; i += 8) {
        int gn = bn + tx;
        tile[i][tx] = (gn < N) ? W[(size_t)(bk + i) * N + gn] : 0.f;
    }
    __syncthreads();
    for (int i = ty; i < 32; i += 8)
        Wt[(size_t)(bn + i) * ldwt + koff + bk + tx] = f2bf(tile[tx][i]);
}

// ======== mega prep kernel: fold1 + weight cvt + bias2c + zero(deg,cur) ========
__global__ __launch_bounds__(256) void prep_all(
    const float* __restrict__ W1, const float* __restrict__ al1, const float* __restrict__ ar1,
    const float* __restrict__ resW1, const float* __restrict__ resW2,
    const float* __restrict__ W2, const float* __restrict__ Wout, const float* __restrict__ b2,
    short* __restrict__ Wcomb, short* __restrict__ W2comb, short* __restrict__ Wtout,
    float* __restrict__ wal1, float* __restrict__ war1,
    float* __restrict__ bias2c, int* __restrict__ zero_base)
{
    int bid = blockIdx.x;
    int t   = threadIdx.x;
    if (bid < 256) {
        int wid  = (bid * 256 + t) >> 6;  // 0..1023
        int lane = t & 63;
        int k = wid >> 2, h = wid & 3;
        const float* wr  = W1  + (size_t)k * 2048 + h * 512;
        const float* alp = al1 + h * 512;
        const float* arp = ar1 + h * 512;
        float sl = 0.f, sr = 0.f;
        for (int j = lane; j < 512; j += 64) {
            float wv = wr[j];
            sl = fmaf(wv, alp[j], sl);
            sr = fmaf(wv, arp[j], sr);
        }
#pragma unroll
        for (int o = 32; o; o >>= 1) { sl += __shfl_down(sl, o); sr += __shfl_down(sr, o); }
        if (lane == 0) { wal1[wid] = sl; war1[wid] = sr; }
    } else if (bid < 1280) {
        int id = bid - 256;               // 1024 blocks: x=64, y=8, z=2
        int bx = id & 63, by = (id >> 6) & 7, bz = id >> 9;
        const float* W = bz ? resW1 : W1;
        cvt_t_body(W, Wcomb, 256, 2048, 512, bz ? 256 : 0,
                   by * 32, bx * 32, t & 31, t >> 5);
    } else if (bid < 1472) {
        int id = bid - 1280;              // 192 blocks: x=4, y=16, z=3
        int bx = id & 3, by = (id >> 2) & 15, bz = id >> 6;
        const float* W; short* Wt; int N;
        if (bz == 0)      { W = W2;    Wt = W2comb;             N = 128; }
        else if (bz == 1) { W = resW2; Wt = W2comb + 128 * 512; N = 128; }
        else              { W = Wout;  Wt = Wtout;              N = 40;  }
        cvt_t_body(W, Wt, 512, N, 512, 0, by * 32, bx * 32, t & 31, t >> 5);
    } else if (bid == 1472) {
        bias2c[t] = (t < 128) ? 0.f : b2[t - 128];
    } else {
        int b = bid - 1473;               // 16 blocks * 256 thr * 16B = 64KB
        int4 z; z.x = 0; z.y = 0; z.z = 0; z.w = 0;
        ((int4*)zero_base)[(size_t)b * 256 + t] = z;
    }
}

// ======== fused front: feat->bf16 + el1/er1 fold + dst histogram ========
__global__ __launch_bounds__(256) void l1_front(
    const float* __restrict__ feat, const float4* __restrict__ wal, const float4* __restrict__ war,
    short* __restrict__ featb, float* __restrict__ el, float* __restrict__ er,
    const int* __restrict__ dst, int* __restrict__ deg, int E, int nfeat)
{
    if ((int)blockIdx.x >= nfeat) {
        int e = (blockIdx.x - nfeat) * 256 + threadIdx.x;
        if (e < E) atomicAdd(&deg[dst[e]], 1);
        return;
    }
    int row  = blockIdx.x * 4 + (threadIdx.x >> 6);
    int lane = threadIdx.x & 63;
    float4 v = ((const float4*)feat)[(size_t)row * 64 + lane];
    short4v o;
    o[0] = f2bf(v.x); o[1] = f2bf(v.y); o[2] = f2bf(v.z); o[3] = f2bf(v.w);
    *(short4v*)(featb + (size_t)row * 256 + lane * 4) = o;

    float fj[4] = { v.x, v.y, v.z, v.w };
    int k = lane * 4;
    float sl[4] = {}, sr[4] = {};
#pragma unroll
    for (int j = 0; j < 4; j++) {
        float4 wl = wal[k + j], wr = war[k + j];
        sl[0] = fmaf(fj[j], wl.x, sl[0]); sl[1] = fmaf(fj[j], wl.y, sl[1]);
        sl[2] = fmaf(fj[j], wl.z, sl[2]); sl[3] = fmaf(fj[j], wl.w, sl[3]);
        sr[0] = fmaf(fj[j], wr.x, sr[0]); sr[1] = fmaf(fj[j], wr.y, sr[1]);
        sr[2] = fmaf(fj[j], wr.z, sr[2]); sr[3] = fmaf(fj[j], wr.w, sr[3]);
    }
#pragma unroll
    for (int o2 = 32; o2; o2 >>= 1) {
#pragma unroll
        for (int h = 0; h < 4; h++) { sl[h] += __shfl_down(sl[h], o2); sr[h] += __shfl_down(sr[h], o2); }
    }
    if (lane == 0) {
#pragma unroll
        for (int h = 0; h < 4; h++) { el[row * 4 + h] = sl[h]; er[row * 4 + h] = sr[h]; }
    }
}

// ======== bf16 MFMA GEMM, BK=64; fused el2/er2 epilogue on n0==0 tiles ========
__global__ __launch_bounds__(256) void gemm_bf16(
    const short* __restrict__ A, const short* __restrict__ Bt,
    const float* __restrict__ bias, void* __restrict__ C,
    int M, int N, int K, int ldc, int nmax, int out_bf16,
    float* __restrict__ el2, float* __restrict__ er2,
    const float* __restrict__ al2, const float* __restrict__ ar2, int do_el)
{
    __shared__ short sA[2][128 * 32];
    __shared__ short sB[2][128 * 32];
    const int tid  = threadIdx.x;
    const int wave = tid >> 6, lane = tid & 63;
    const int wm = wave >> 1, wn = wave & 1;
    int lid = xcd_logical_id();
    const int bx = lid % gridDim.x, by = lid / gridDim.x;
    const int m0 = by * 128, n0 = bx * 128;

    const int srow = tid >> 2;
    const int scol = (tid & 3) * 8;
    const int fr = lane & 15;
    const int fq = lane >> 4;

    f32x4 acc[4][4] = {};

    for (int k0 = 0; k0 < K; k0 += 64) {
#pragma unroll
        for (int hh = 0; hh < 2; hh++) {
            int kc = k0 + hh * 32 + scol;
            const short* ga0 = A  + (size_t)(m0 + srow) * K + kc;
            const short* ga1 = A  + (size_t)(m0 + 64 + srow) * K + kc;
            const short* gb0 = Bt + (size_t)(n0 + srow) * K + kc;
            const short* gb1 = Bt + (size_t)(n0 + 64 + srow) * K + kc;
            __builtin_amdgcn_global_load_lds((const __attribute__((address_space(1))) void*)ga0,
                (__attribute__((address_space(3))) void*)(sA[hh] + wave * 512), 16, 0, 0);
            __builtin_amdgcn_global_load_lds((const __attribute__((address_space(1))) void*)ga1,
                (__attribute__((address_space(3))) void*)(sA[hh] + 2048 + wave * 512), 16, 0, 0);
            __builtin_amdgcn_global_load_lds((const __attribute__((address_space(1))) void*)gb0,
                (__attribute__((address_space(3))) void*)(sB[hh] + wave * 512), 16, 0, 0);
            __builtin_amdgcn_global_load_lds((const __attribute__((address_space(1))) void*)gb1,
                (__attribute__((address_space(3))) void*)(sB[hh] + 2048 + wave * 512), 16, 0, 0);
        }
        __syncthreads();

#pragma unroll
        for (int hh = 0; hh < 2; hh++) {
            bf16x8 af[4], bfr[4];
#pragma unroll
            for (int m = 0; m < 4; m++)
                af[m] = *(const bf16x8*)(sA[hh] + (wm * 64 + m * 16 + fr) * 32 + fq * 8);
#pragma unroll
            for (int n = 0; n < 4; n++)
                bfr[n] = *(const bf16x8*)(sB[hh] + (wn * 64 + n * 16 + fr) * 32 + fq * 8);
#pragma unroll
            for (int m = 0; m < 4; m++)
#pragma unroll
                for (int n = 0; n < 4; n++)
                    acc[m][n] = __builtin_amdgcn_mfma_f32_16x16x32_bf16(af[m], bfr[n], acc[m][n], 0, 0, 0);
        }
        __syncthreads();
    }

    if (do_el && bx == 0) {
        float cal[4], car[4];
#pragma unroll
        for (int n = 0; n < 4; n++) {
            cal[n] = al2[wn * 64 + n * 16 + fr];
            car[n] = ar2[wn * 64 + n * 16 + fr];
        }
#pragma unroll
        for (int m = 0; m < 4; m++) {
#pragma unroll
            for (int j = 0; j < 4; j++) {
                float ell = acc[m][0][j] * cal[0] + acc[m][1][j] * cal[1];
                float elh = acc[m][2][j] * cal[2] + acc[m][3][j] * cal[3];
                float erl = acc[m][0][j] * car[0] + acc[m][1][j] * car[1];
                float erh = acc[m][2][j] * car[2] + acc[m][3][j] * car[3];
#pragma unroll
                for (int o = 1; o < 16; o <<= 1) {
                    ell += __shfl_xor(ell, o);
                    elh += __shfl_xor(elh, o);
                    erl += __shfl_xor(erl, o);
                    erh += __shfl_xor(erh, o);
                }
                if (fr == 0) {
                    int R = m0 + wm * 64 + m * 16 + fq * 4 + j;
                    el2[R * 4 + wn * 2]     = ell;
                    el2[R * 4 + wn * 2 + 1] = elh;
                    er2[R * 4 + wn * 2]     = erl;
                    er2[R * 4 + wn * 2 + 1] = erh;
                }
            }
        }
    }

#pragma unroll
    for (int n = 0; n < 4; n++) {
        int gcol = n0 + wn * 64 + n * 16 + fr;
        if (gcol >= nmax) continue;
        float bv = bias ? bias[gcol] : 0.f;
#pragma unroll
        for (int m = 0; m < 4; m++) {
#pragma unroll
            for (int j = 0; j < 4; j++) {
                int grow = m0 + wm * 64 + m * 16 + fq * 4 + j;
                float v = acc[m][n][j] + bv;
                if (out_bf16) ((short*)C)[(size_t)grow * ldc + gcol] = f2bf(v);
                else          ((float*)C)[(size_t)grow * ldc + gcol] = v;
            }
        }
    }
}

// ======== batched-by-head GEMM, BK=64: h1 = relu([agg|feat] @ [W1|resW1]_h^T + b1) ========
__global__ __launch_bounds__(256) void gemm_h1(
    const short* __restrict__ Acomb, const short* __restrict__ featb,
    const short* __restrict__ Wcomb, const float* __restrict__ b1, short* __restrict__ h1b)
{
    __shared__ short sA[2][128 * 32];
    __shared__ short sB[2][128 * 32];
    const int tid  = threadIdx.x;
    const int wave = tid >> 6, lane = tid & 63;
    const int wm = wave >> 1, wn = wave & 1;
    int lid = xcd_logical_id();                  // grid (4, M/128, 4)
    const int bx = lid & 3;
    const int by = (lid >> 2) % gridDim.y;
    const int h  = lid / (gridDim.y * 4);
    const int m0 = by * 128, n0 = bx * 128;
    const short* Bt = Wcomb + (size_t)(h * 512) * 512;

    const int srow = tid >> 2;
    const int scol = (tid & 3) * 8;
    const int fr = lane & 15;
    const int fq = lane >> 4;

    f32x4 acc[4][4] = {};

    for (int k0 = 0; k0 < 512; k0 += 64) {
        const int res_half = (k0 >= 256);
#pragma unroll
        for (int hh = 0; hh < 2; hh++) {
            int kc = k0 + hh * 32 + scol;
            const short* ga0;
            const short* ga1;
            if (!res_half) {
                ga0 = Acomb + ((size_t)(m0 + srow) * 4 + h) * 256 + kc;
                ga1 = Acomb + ((size_t)(m0 + 64 + srow) * 4 + h) * 256 + kc;
            } else {
                ga0 = featb + (size_t)(m0 + srow) * 256 + (kc - 256);
                ga1 = featb + (size_t)(m0 + 64 + srow) * 256 + (kc - 256);
            }
            const short* gb0 = Bt + (size_t)(n0 + srow) * 512 + kc;
            const short* gb1 = Bt + (size_t)(n0 + 64 + srow) * 512 + kc;
            __builtin_amdgcn_global_load_lds((const __attribute__((address_space(1))) void*)ga0,
                (__attribute__((address_space(3))) void*)(sA[hh] + wave * 512), 16, 0, 0);
            __builtin_amdgcn_global_load_lds((const __attribute__((address_space(1))) void*)ga1,
                (__attribute__((address_space(3))) void*)(sA[hh] + 2048 + wave * 512), 16, 0, 0);
            __builtin_amdgcn_global_load_lds((const __attribute__((address_space(1))) void*)gb0,
                (__attribute__((address_space(3))) void*)(sB[hh] + wave * 512), 16, 0, 0);
            __builtin_amdgcn_global_load_lds((const __attribute__((address_space(1))) void*)gb1,
                (__attribute__((address_space(3))) void*)(sB[hh] + 2048 + wave * 512), 16, 0, 0);
        }
        __syncthreads();

#pragma unroll
        for (int hh = 0; hh < 2; hh++) {
            bf16x8 af[4], bfr[4];
#pragma unroll
            for (int m = 0; m < 4; m++)
                af[m] = *(const bf16x8*)(sA[hh] + (wm * 64 + m * 16 + fr) * 32 + fq * 8);
#pragma unroll
            for (int n = 0; n < 4; n++)
                bfr[n] = *(const bf16x8*)(sB[hh] + (wn * 64 + n * 16 + fr) * 32 + fq * 8);
#pragma unroll
            for (int m = 0; m < 4; m++)
#pragma unroll
                for (int n = 0; n < 4; n++)
                    acc[m][n] = __builtin_amdgcn_mfma_f32_16x16x32_bf16(af[m], bfr[n], acc[m][n], 0, 0, 0);
        }
        __syncthreads();
    }

#pragma unroll
    for (int n = 0; n < 4; n++) {
        int gcol = h * 512 + n0 + wn * 64 + n * 16 + fr;
        float bv = b1[gcol];
#pragma unroll
        for (int m = 0; m < 4; m++) {
#pragma unroll
            for (int j = 0; j < 4; j++) {
                int grow = m0 + wm * 64 + m * 16 + fq * 4 + j;
                float v = acc[m][n][j] + bv;
                h1b[(size_t)grow * 2048 + gcol] = f2bf(v > 0.f ? v : 0.f);
            }
        }
    }
}

// ======== CSR scan + scatter ========
__global__ __launch_bounds__(1024) void scan_excl(const int* __restrict__ deg,
                                                  int* __restrict__ off, int N)
{
    __shared__ int part[1024];
    int t = threadIdx.x;
    int chunk = N >> 10;
    int base = t * chunk;
    int local[16];
    int s = 0;
    for (int i = 0; i < chunk; i++) { local[i] = s; s += deg[base + i]; }
    part[t] = s;
    __syncthreads();
    for (int o = 1; o < 1024; o <<= 1) {
        int v = (t >= o) ? part[t - o] : 0;
        __syncthreads();
        part[t] += v;
        __syncthreads();
    }
    int pre = (t == 0) ? 0 : part[t - 1];
    for (int i = 0; i < chunk; i++) off[base + i] = pre + local[i];
    if (t == 1023) off[N] = pre + s;
}

__global__ void scatter_kernel(const int* __restrict__ dst, const int* __restrict__ off,
                               int* __restrict__ cur, int* __restrict__ eid, int E)
{
    int e = blockIdx.x * blockDim.x + threadIdx.x;
    if (e < E) {
        int d = dst[e];
        int p = off[d] + atomicAdd(&cur[d], 1);
        eid[p] = e;
    }
}

// ======== L1: fused edge-softmax + feature aggregation -> slim Acomb [N*4,256] ========
__global__ __launch_bounds__(256) void aggregate_feat_sm(
    const int* __restrict__ off, const int* __restrict__ eid, const int* __restrict__ src,
    const float* __restrict__ el, const float* __restrict__ er,
    const short* __restrict__ featb, short* __restrict__ Acomb)
{
    int wv = threadIdx.x >> 6, lane = threadIdx.x & 63;
    int n = blockIdx.x * 4 + wv;
    int k4 = lane * 4;
    float4 erv = ((const float4*)er)[n];
    float acc[4][4] = {};
    float accd[4] = {};
    int beg = off[n], end = off[n + 1];
    for (int j = beg; j < end; ++j) {
        int e = eid[j];
        int s = src[e];
        float4 elv = ((const float4*)el)[s];
        float a0 = elv.x + erv.x, a1 = elv.y + erv.y, a2 = elv.z + erv.z, a3 = elv.w + erv.w;
        a0 = __expf(a0 > 0.f ? a0 : 0.2f * a0);
        a1 = __expf(a1 > 0.f ? a1 : 0.2f * a1);
        a2 = __expf(a2 > 0.f ? a2 : 0.2f * a2);
        a3 = __expf(a3 > 0.f ? a3 : 0.2f * a3);
        accd[0] += a0; accd[1] += a1; accd[2] += a2; accd[3] += a3;
        short4v fv = *(const short4v*)(featb + (size_t)s * 256 + k4);
        float f0 = b2f(fv[0]), f1 = b2f(fv[1]), f2 = b2f(fv[2]), f3 = b2f(fv[3]);
        acc[0][0] = fmaf(a0, f0, acc[0][0]); acc[0][1] = fmaf(a0, f1, acc[0][1]);
        acc[0][2] = fmaf(a0, f2, acc[0][2]); acc[0][3] = fmaf(a0, f3, acc[0][3]);
        acc[1][0] = fmaf(a1, f0, acc[1][0]); acc[1][1] = fmaf(a1, f1, acc[1][1]);
        acc[1][2] = fmaf(a1, f2, acc[1][2]); acc[1][3] = fmaf(a1, f3, acc[1][3]);
        acc[2][0] = fmaf(a2, f0, acc[2][0]); acc[2][1] = fmaf(a2, f1, acc[2][1]);
        acc[2][2] = fmaf(a2, f2, acc[2][2]); acc[2][3] = fmaf(a2, f3, acc[2][3]);
        acc[3][0] = fmaf(a3, f0, acc[3][0]); acc[3][1] = fmaf(a3, f1, acc[3][1]);
        acc[3][2] = fmaf(a3, f2, acc[3][2]); acc[3][3] = fmaf(a3, f3, acc[3][3]);
    }
    float inv[4];
#pragma unroll
    for (int h = 0; h < 4; h++) inv[h] = 1.f / (accd[h] == 0.f ? 1.f : accd[h]);
#pragma unroll
    for (int h = 0; h < 4; h++) {
        short4v o;
#pragma unroll
        for (int kk = 0; kk < 4; kk++) o[kk] = f2bf(acc[h][kk] * inv[h]);
        *(short4v*)(Acomb + ((size_t)n * 4 + h) * 256 + k4) = o;
    }
}

// ======== L2: fused edge-softmax + aggregation + OUTPUT PROJECTION ========
// wave per node (4 nodes/block). Lane owns h2 flat cols [lane*8, lane*8+8) in regs:
// flat k = p*128 + colin + i  with p=lane>>4, colin=(lane&15)*8  ==> k = lane*8+i.
// Then out[n,c] = sum_k h2[k]*Wtout[c*512+k] + bout[c] via LDS-staged Wtout.
__global__ __launch_bounds__(256) void aggregate2_out(
    const int* __restrict__ off, const int* __restrict__ eid, const int* __restrict__ src,
    const float* __restrict__ el, const float* __restrict__ er,
    const short* __restrict__ z2res, const short* __restrict__ Wtout,
    const float* __restrict__ bout, float* __restrict__ out)
{
    __shared__ short sW[40 * 512];   // 40 KB
    // cooperative Wtout stage (rows 0..39 valid)
    for (int i = threadIdx.x; i < 40 * 512 / 8; i += 256)
        *(bf16x8*)(sW + (size_t)i * 8) = *(const bf16x8*)(Wtout + (size_t)i * 8);

    int wv = threadIdx.x >> 6, lane = threadIdx.x & 63;
    int n = blockIdx.x * 4 + wv;
    int p = lane >> 4;                 // z2res sub-row
    int colin = (lane & 15) * 8;       // col within 128 z2 cols
    int c = p * 4 + (colin >> 5);      // channel 0..15
    float erv = er[n * 16 + c];
    float r[8] = {};
    float dn = 0.f;
    int beg = off[n], end = off[n + 1];
    for (int j = beg; j < end; ++j) {
        int e = eid[j];
        int s = src[e];
        float lv = el[s * 16 + c] + erv;
        float a = __expf(lv > 0.f ? lv : 0.2f * lv);
        dn += a;
        bf16x8 zv = *(const bf16x8*)(z2res + ((size_t)s * 4 + p) * 256 + colin);
#pragma unroll
        for (int i = 0; i < 8; ++i) r[i] = fmaf(a, b2f(zv[i]), r[i]);
    }
    if (dn == 0.f) dn = 1.f;
    float inv = 1.f / dn;
    bf16x8 rv = *(const bf16x8*)(z2res + ((size_t)n * 4 + p) * 256 + 128 + colin);
    float h2v[8];
#pragma unroll
    for (int i = 0; i < 8; ++i) {
        float v = r[i] * inv + b2f(rv[i]);
        h2v[i] = v > 0.f ? v : 0.f;    // fp32 h2, never materialized
    }
    __syncthreads();                    // sW ready

    // out projection: 40 cols, each = 512-dot (8/lane + 6-step reduce)
    for (int c2 = 0; c2 < 40; c2++) {
        bf16x8 w8 = *(const bf16x8*)(sW + c2 * 512 + lane * 8);
        float s = 0.f;
#pragma unroll
        for (int i = 0; i < 8; ++i) s = fmaf(h2v[i], b2f(w8[i]), s);
#pragma unroll
        for (int o = 32; o; o >>= 1) s += __shfl_down(s, o);
        if (lane == 0) out[(size_t)n * 40 + c2] = s + bout[c2];
    }
}

// ======== launch ========
extern "C" void kernel_launch(void* const* d_in, const int* in_sizes, int n_in,
                              void* d_out, int out_size, void* d_ws, size_t ws_size,
                              hipStream_t stream)
{
    const float* feat  = (const float*)d_in[0];
    const int*   src   = (const int*)d_in[1];
    const int*   dst   = (const int*)d_in[2];
    const float* W1    = (const float*)d_in[3];
    const float* al1   = (const float*)d_in[4];
    const float* ar1   = (const float*)d_in[5];
    const float* resW1 = (const float*)d_in[6];
    const float* b1    = (const float*)d_in[7];
    const float* W2    = (const float*)d_in[8];
    const float* al2   = (const float*)d_in[9];
    const float* ar2   = (const float*)d_in[10];
    const float* resW2 = (const float*)d_in[11];
    const float* b2    = (const float*)d_in[12];
    const float* Wout  = (const float*)d_in[13];
    const float* bout  = (const float*)d_in[14];
    const int N = in_sizes[0] / IN_F;  // 8192
    const int E = in_sizes[1];         // 65536

    // ---- workspace layout (~72 MB) ----
    char* w = (char*)d_ws;
    auto alloc = [&](size_t bytes) -> char* {
        char* p = w;
        w += (bytes + 255) & ~(size_t)255;
        return p;
    };
    short*    Acomb   = (short*)alloc((size_t)N * 4 * 256 * 2);   // 16 MB (slim)
    short*    h1b     = (short*)alloc((size_t)N * 2048 * 2);      // 32 MB
    short*    featb   = (short*)alloc((size_t)N * 256 * 2);       // 4 MB
    short*    Wcomb   = (short*)alloc((size_t)2048 * 512 * 2);    // 2 MB
    short*    W2comb  = (short*)alloc((size_t)256 * 512 * 2);
    short*    Wtout   = (short*)alloc((size_t)128 * 512 * 2);
    float*    bias2c  = (float*)alloc((size_t)256 * 4);
    float*    wal1    = (float*)alloc((size_t)256 * 4 * 4);
    float*    war1    = (float*)alloc((size_t)256 * 4 * 4);
    float*    el1     = (float*)alloc((size_t)N * 4 * 4);
    float*    er1     = (float*)alloc((size_t)N * 4 * 4);
    int*      deg     = (int*)alloc((size_t)N * 4);               // deg+cur contiguous:
    int*      cur     = (int*)alloc((size_t)N * 4);               //   prep_all zeroes both
    int*      off     = (int*)alloc((size_t)(N + 1) * 4);
    int*      eid     = (int*)alloc((size_t)E * 4);
    short*    z2res   = (short*)alloc((size_t)N * 4 * 256 * 2);   // 16 MB
    float*    el2     = (float*)alloc((size_t)N * 16 * 4);
    float*    er2     = (float*)alloc((size_t)N * 16 * 4);

    dim3 blk(256);

    // ===== prep: fold1 + weight cvt + bias2c + zero(deg,cur) =====
    prep_all<<<dim3(1489), blk, 0, stream>>>(W1, al1, ar1, resW1, resW2, W2, Wout, b2,
                                             Wcomb, W2comb, Wtout,
                                             wal1, war1, bias2c, deg);

    // ===== front: feat cvt + el1/er1 + dst histogram (one dispatch) =====
    l1_front<<<dim3(N / 4 + E / 256), blk, 0, stream>>>(feat, (const float4*)wal1, (const float4*)war1,
                                                        featb, el1, er1, dst, deg, E, N / 4);
    scan_excl<<<dim3(1), dim3(1024), 0, stream>>>(deg, off, N);
    scatter_kernel<<<dim3((E + 255) / 256), blk, 0, stream>>>(dst, off, cur, eid, E);

    // ===== layer 1 =====
    aggregate_feat_sm<<<dim3(N / 4), blk, 0, stream>>>(off, eid, src, el1, er1, featb, Acomb);
    gemm_h1<<<dim3(4, N / 128, 4), blk, 0, stream>>>(Acomb, featb, Wcomb, b1, h1b);
    // h1b = bf16 h1 [N,4,512]

    // ===== layer 2 (GEMM with fused el2/er2 epilogue) =====
    gemm_bf16<<<dim3(2, (N * 4) / 128), blk, 0, stream>>>(h1b, W2comb, bias2c, z2res,
                                                          N * 4, 256, 512, 256, 256, 1,
                                                          el2, er2, al2, ar2, 1);

    // ===== layer-2 aggregation + final linear fused =====
    aggregate2_out<<<dim3(N / 4), blk, 0, stream>>>(off, eid, src, el2, er2, z2res,
                                                    Wtout, bout, (float*)d_out);
}

// Round 13
// 135.004 us; speedup vs baseline: 1.1468x; 1.1468x over previous
//
#include <hip/hip_runtime.h>
#include <cmath>

constexpr int IN_F  = 256;

typedef short bf16x8 __attribute__((ext_vector_type(8)));
typedef short short4v __attribute__((ext_vector_type(4)));
typedef float f32x4 __attribute__((ext_vector_type(4)));

__device__ __forceinline__ short f2bf(float f) {
    unsigned u = __float_as_uint(f);
    unsigned r = (u + 0x7FFFu + ((u >> 16) & 1)) >> 16;  // RNE
    return (short)r;
}
__device__ __forceinline__ float b2f(short s) {
    return __uint_as_float(((unsigned)(unsigned short)s) << 16);
}

// ======== XCD-chunked block swizzle (T1) ========
__device__ __forceinline__ int xcd_logical_id()
{
    int nx = gridDim.x, ny = gridDim.y, nz = gridDim.z;
    int flat = blockIdx.x + nx * (blockIdx.y + ny * blockIdx.z);
    int nwg = nx * ny * nz;
    if (nwg & 7) return flat;
    int chunk = nwg >> 3;
    return (flat & 7) * chunk + (flat >> 3);
}

// ======== weight transpose to bf16 (device helper; 32x32 tile) ========
__device__ __forceinline__ void cvt_t_body(
    const float* __restrict__ W, short* __restrict__ Wt, int K, int N,
    int ldwt, int koff, int bk, int bn, int tx, int ty)
{
    __shared__ float tile[32][33];
    for (int i = ty; i < 32; i += 8) {
        int gn = bn + tx;
        tile[i][tx] = (gn < N) ? W[(size_t)(bk + i) * N + gn] : 0.f;
    }
    __syncthreads();
    for (int i = ty; i < 32; i += 8)
        Wt[(size_t)(bn + i) * ldwt + koff + bk + tx] = f2bf(tile[tx][i]);
}

// ======== mega prep kernel: fold1 + weight cvt + bias2c + zero(deg,cur) ========
__global__ __launch_bounds__(256) void prep_all(
    const float* __restrict__ W1, const float* __restrict__ al1, const float* __restrict__ ar1,
    const float* __restrict__ resW1, const float* __restrict__ resW2,
    const float* __restrict__ W2, const float* __restrict__ Wout, const float* __restrict__ b2,
    short* __restrict__ Wcomb, short* __restrict__ W2comb, short* __restrict__ Wtout,
    float* __restrict__ wal1, float* __restrict__ war1,
    float* __restrict__ bias2c, int* __restrict__ zero_base)
{
    int bid = blockIdx.x;
    int t   = threadIdx.x;
    if (bid < 256) {
        int wid  = (bid * 256 + t) >> 6;  // 0..1023
        int lane = t & 63;
        int k = wid >> 2, h = wid & 3;
        const float* wr  = W1  + (size_t)k * 2048 + h * 512;
        const float* alp = al1 + h * 512;
        const float* arp = ar1 + h * 512;
        float sl = 0.f, sr = 0.f;
        for (int j = lane; j < 512; j += 64) {
            float wv = wr[j];
            sl = fmaf(wv, alp[j], sl);
            sr = fmaf(wv, arp[j], sr);
        }
#pragma unroll
        for (int o = 32; o; o >>= 1) { sl += __shfl_down(sl, o); sr += __shfl_down(sr, o); }
        if (lane == 0) { wal1[wid] = sl; war1[wid] = sr; }
    } else if (bid < 1280) {
        int id = bid - 256;               // 1024 blocks: x=64, y=8, z=2
        int bx = id & 63, by = (id >> 6) & 7, bz = id >> 9;
        const float* W = bz ? resW1 : W1;
        cvt_t_body(W, Wcomb, 256, 2048, 512, bz ? 256 : 0,
                   by * 32, bx * 32, t & 31, t >> 5);
    } else if (bid < 1472) {
        int id = bid - 1280;              // 192 blocks: x=4, y=16, z=3
        int bx = id & 3, by = (id >> 2) & 15, bz = id >> 6;
        const float* W; short* Wt; int N;
        if (bz == 0)      { W = W2;    Wt = W2comb;             N = 128; }
        else if (bz == 1) { W = resW2; Wt = W2comb + 128 * 512; N = 128; }
        else              { W = Wout;  Wt = Wtout;              N = 40;  }
        cvt_t_body(W, Wt, 512, N, 512, 0, by * 32, bx * 32, t & 31, t >> 5);
    } else if (bid == 1472) {
        bias2c[t] = (t < 128) ? 0.f : b2[t - 128];
    } else {
        int b = bid - 1473;               // 16 blocks * 256 thr * 16B = 64KB
        int4 z; z.x = 0; z.y = 0; z.z = 0; z.w = 0;
        ((int4*)zero_base)[(size_t)b * 256 + t] = z;
    }
}

// ======== fused front: feat->bf16 + el1/er1 fold + dst histogram ========
__global__ __launch_bounds__(256) void l1_front(
    const float* __restrict__ feat, const float4* __restrict__ wal, const float4* __restrict__ war,
    short* __restrict__ featb, float* __restrict__ el, float* __restrict__ er,
    const int* __restrict__ dst, int* __restrict__ deg, int E, int nfeat)
{
    if ((int)blockIdx.x >= nfeat) {
        int e = (blockIdx.x - nfeat) * 256 + threadIdx.x;
        if (e < E) atomicAdd(&deg[dst[e]], 1);
        return;
    }
    int row  = blockIdx.x * 4 + (threadIdx.x >> 6);
    int lane = threadIdx.x & 63;
    float4 v = ((const float4*)feat)[(size_t)row * 64 + lane];
    short4v o;
    o[0] = f2bf(v.x); o[1] = f2bf(v.y); o[2] = f2bf(v.z); o[3] = f2bf(v.w);
    *(short4v*)(featb + (size_t)row * 256 + lane * 4) = o;

    float fj[4] = { v.x, v.y, v.z, v.w };
    int k = lane * 4;
    float sl[4] = {}, sr[4] = {};
#pragma unroll
    for (int j = 0; j < 4; j++) {
        float4 wl = wal[k + j], wr = war[k + j];
        sl[0] = fmaf(fj[j], wl.x, sl[0]); sl[1] = fmaf(fj[j], wl.y, sl[1]);
        sl[2] = fmaf(fj[j], wl.z, sl[2]); sl[3] = fmaf(fj[j], wl.w, sl[3]);
        sr[0] = fmaf(fj[j], wr.x, sr[0]); sr[1] = fmaf(fj[j], wr.y, sr[1]);
        sr[2] = fmaf(fj[j], wr.z, sr[2]); sr[3] = fmaf(fj[j], wr.w, sr[3]);
    }
#pragma unroll
    for (int o2 = 32; o2; o2 >>= 1) {
#pragma unroll
        for (int h = 0; h < 4; h++) { sl[h] += __shfl_down(sl[h], o2); sr[h] += __shfl_down(sr[h], o2); }
    }
    if (lane == 0) {
#pragma unroll
        for (int h = 0; h < 4; h++) { el[row * 4 + h] = sl[h]; er[row * 4 + h] = sr[h]; }
    }
}

// ======== bf16 MFMA GEMM, BK=64; fused el2/er2 epilogue on n0==0 tiles ========
__global__ __launch_bounds__(256) void gemm_bf16(
    const short* __restrict__ A, const short* __restrict__ Bt,
    const float* __restrict__ bias, void* __restrict__ C,
    int M, int N, int K, int ldc, int nmax, int out_bf16,
    float* __restrict__ el2, float* __restrict__ er2,
    const float* __restrict__ al2, const float* __restrict__ ar2, int do_el)
{
    __shared__ short sA[2][128 * 32];
    __shared__ short sB[2][128 * 32];
    const int tid  = threadIdx.x;
    const int wave = tid >> 6, lane = tid & 63;
    const int wm = wave >> 1, wn = wave & 1;
    int lid = xcd_logical_id();
    const int bx = lid % gridDim.x, by = lid / gridDim.x;
    const int m0 = by * 128, n0 = bx * 128;

    const int srow = tid >> 2;
    const int scol = (tid & 3) * 8;
    const int fr = lane & 15;
    const int fq = lane >> 4;

    f32x4 acc[4][4] = {};

    for (int k0 = 0; k0 < K; k0 += 64) {
#pragma unroll
        for (int hh = 0; hh < 2; hh++) {
            int kc = k0 + hh * 32 + scol;
            const short* ga0 = A  + (size_t)(m0 + srow) * K + kc;
            const short* ga1 = A  + (size_t)(m0 + 64 + srow) * K + kc;
            const short* gb0 = Bt + (size_t)(n0 + srow) * K + kc;
            const short* gb1 = Bt + (size_t)(n0 + 64 + srow) * K + kc;
            __builtin_amdgcn_global_load_lds((const __attribute__((address_space(1))) void*)ga0,
                (__attribute__((address_space(3))) void*)(sA[hh] + wave * 512), 16, 0, 0);
            __builtin_amdgcn_global_load_lds((const __attribute__((address_space(1))) void*)ga1,
                (__attribute__((address_space(3))) void*)(sA[hh] + 2048 + wave * 512), 16, 0, 0);
            __builtin_amdgcn_global_load_lds((const __attribute__((address_space(1))) void*)gb0,
                (__attribute__((address_space(3))) void*)(sB[hh] + wave * 512), 16, 0, 0);
            __builtin_amdgcn_global_load_lds((const __attribute__((address_space(1))) void*)gb1,
                (__attribute__((address_space(3))) void*)(sB[hh] + 2048 + wave * 512), 16, 0, 0);
        }
        __syncthreads();

#pragma unroll
        for (int hh = 0; hh < 2; hh++) {
            bf16x8 af[4], bfr[4];
#pragma unroll
            for (int m = 0; m < 4; m++)
                af[m] = *(const bf16x8*)(sA[hh] + (wm * 64 + m * 16 + fr) * 32 + fq * 8);
#pragma unroll
            for (int n = 0; n < 4; n++)
                bfr[n] = *(const bf16x8*)(sB[hh] + (wn * 64 + n * 16 + fr) * 32 + fq * 8);
#pragma unroll
            for (int m = 0; m < 4; m++)
#pragma unroll
                for (int n = 0; n < 4; n++)
                    acc[m][n] = __builtin_amdgcn_mfma_f32_16x16x32_bf16(af[m], bfr[n], acc[m][n], 0, 0, 0);
        }
        __syncthreads();
    }

    if (do_el && bx == 0) {
        float cal[4], car[4];
#pragma unroll
        for (int n = 0; n < 4; n++) {
            cal[n] = al2[wn * 64 + n * 16 + fr];
            car[n] = ar2[wn * 64 + n * 16 + fr];
        }
#pragma unroll
        for (int m = 0; m < 4; m++) {
#pragma unroll
            for (int j = 0; j < 4; j++) {
                float ell = acc[m][0][j] * cal[0] + acc[m][1][j] * cal[1];
                float elh = acc[m][2][j] * cal[2] + acc[m][3][j] * cal[3];
                float erl = acc[m][0][j] * car[0] + acc[m][1][j] * car[1];
                float erh = acc[m][2][j] * car[2] + acc[m][3][j] * car[3];
#pragma unroll
                for (int o = 1; o < 16; o <<= 1) {
                    ell += __shfl_xor(ell, o);
                    elh += __shfl_xor(elh, o);
                    erl += __shfl_xor(erl, o);
                    erh += __shfl_xor(erh, o);
                }
                if (fr == 0) {
                    int R = m0 + wm * 64 + m * 16 + fq * 4 + j;
                    el2[R * 4 + wn * 2]     = ell;
                    el2[R * 4 + wn * 2 + 1] = elh;
                    er2[R * 4 + wn * 2]     = erl;
                    er2[R * 4 + wn * 2 + 1] = erh;
                }
            }
        }
    }

#pragma unroll
    for (int n = 0; n < 4; n++) {
        int gcol = n0 + wn * 64 + n * 16 + fr;
        if (gcol >= nmax) continue;
        float bv = bias ? bias[gcol] : 0.f;
#pragma unroll
        for (int m = 0; m < 4; m++) {
#pragma unroll
            for (int j = 0; j < 4; j++) {
                int grow = m0 + wm * 64 + m * 16 + fq * 4 + j;
                float v = acc[m][n][j] + bv;
                if (out_bf16) ((short*)C)[(size_t)grow * ldc + gcol] = f2bf(v);
                else          ((float*)C)[(size_t)grow * ldc + gcol] = v;
            }
        }
    }
}

// ======== batched-by-head GEMM, BK=64: h1 = relu([agg|feat] @ [W1|resW1]_h^T + b1) ========
__global__ __launch_bounds__(256) void gemm_h1(
    const short* __restrict__ Acomb, const short* __restrict__ featb,
    const short* __restrict__ Wcomb, const float* __restrict__ b1, short* __restrict__ h1b)
{
    __shared__ short sA[2][128 * 32];
    __shared__ short sB[2][128 * 32];
    const int tid  = threadIdx.x;
    const int wave = tid >> 6, lane = tid & 63;
    const int wm = wave >> 1, wn = wave & 1;
    int lid = xcd_logical_id();                  // grid (4, M/128, 4)
    const int bx = lid & 3;
    const int by = (lid >> 2) % gridDim.y;
    const int h  = lid / (gridDim.y * 4);
    const int m0 = by * 128, n0 = bx * 128;
    const short* Bt = Wcomb + (size_t)(h * 512) * 512;

    const int srow = tid >> 2;
    const int scol = (tid & 3) * 8;
    const int fr = lane & 15;
    const int fq = lane >> 4;

    f32x4 acc[4][4] = {};

    for (int k0 = 0; k0 < 512; k0 += 64) {
        const int res_half = (k0 >= 256);
#pragma unroll
        for (int hh = 0; hh < 2; hh++) {
            int kc = k0 + hh * 32 + scol;
            const short* ga0;
            const short* ga1;
            if (!res_half) {
                ga0 = Acomb + ((size_t)(m0 + srow) * 4 + h) * 256 + kc;
                ga1 = Acomb + ((size_t)(m0 + 64 + srow) * 4 + h) * 256 + kc;
            } else {
                ga0 = featb + (size_t)(m0 + srow) * 256 + (kc - 256);
                ga1 = featb + (size_t)(m0 + 64 + srow) * 256 + (kc - 256);
            }
            const short* gb0 = Bt + (size_t)(n0 + srow) * 512 + kc;
            const short* gb1 = Bt + (size_t)(n0 + 64 + srow) * 512 + kc;
            __builtin_amdgcn_global_load_lds((const __attribute__((address_space(1))) void*)ga0,
                (__attribute__((address_space(3))) void*)(sA[hh] + wave * 512), 16, 0, 0);
            __builtin_amdgcn_global_load_lds((const __attribute__((address_space(1))) void*)ga1,
                (__attribute__((address_space(3))) void*)(sA[hh] + 2048 + wave * 512), 16, 0, 0);
            __builtin_amdgcn_global_load_lds((const __attribute__((address_space(1))) void*)gb0,
                (__attribute__((address_space(3))) void*)(sB[hh] + wave * 512), 16, 0, 0);
            __builtin_amdgcn_global_load_lds((const __attribute__((address_space(1))) void*)gb1,
                (__attribute__((address_space(3))) void*)(sB[hh] + 2048 + wave * 512), 16, 0, 0);
        }
        __syncthreads();

#pragma unroll
        for (int hh = 0; hh < 2; hh++) {
            bf16x8 af[4], bfr[4];
#pragma unroll
            for (int m = 0; m < 4; m++)
                af[m] = *(const bf16x8*)(sA[hh] + (wm * 64 + m * 16 + fr) * 32 + fq * 8);
#pragma unroll
            for (int n = 0; n < 4; n++)
                bfr[n] = *(const bf16x8*)(sB[hh] + (wn * 64 + n * 16 + fr) * 32 + fq * 8);
#pragma unroll
            for (int m = 0; m < 4; m++)
#pragma unroll
                for (int n = 0; n < 4; n++)
                    acc[m][n] = __builtin_amdgcn_mfma_f32_16x16x32_bf16(af[m], bfr[n], acc[m][n], 0, 0, 0);
        }
        __syncthreads();
    }

#pragma unroll
    for (int n = 0; n < 4; n++) {
        int gcol = h * 512 + n0 + wn * 64 + n * 16 + fr;
        float bv = b1[gcol];
#pragma unroll
        for (int m = 0; m < 4; m++) {
#pragma unroll
            for (int j = 0; j < 4; j++) {
                int grow = m0 + wm * 64 + m * 16 + fq * 4 + j;
                float v = acc[m][n][j] + bv;
                h1b[(size_t)grow * 2048 + gcol] = f2bf(v > 0.f ? v : 0.f);
            }
        }
    }
}

// ======== CSR scan + scatter ========
__global__ __launch_bounds__(1024) void scan_excl(const int* __restrict__ deg,
                                                  int* __restrict__ off, int N)
{
    __shared__ int part[1024];
    int t = threadIdx.x;
    int chunk = N >> 10;
    int base = t * chunk;
    int local[16];
    int s = 0;
    for (int i = 0; i < chunk; i++) { local[i] = s; s += deg[base + i]; }
    part[t] = s;
    __syncthreads();
    for (int o = 1; o < 1024; o <<= 1) {
        int v = (t >= o) ? part[t - o] : 0;
        __syncthreads();
        part[t] += v;
        __syncthreads();
    }
    int pre = (t == 0) ? 0 : part[t - 1];
    for (int i = 0; i < chunk; i++) off[base + i] = pre + local[i];
    if (t == 1023) off[N] = pre + s;
}

__global__ void scatter_kernel(const int* __restrict__ dst, const int* __restrict__ off,
                               int* __restrict__ cur, int* __restrict__ eid, int E)
{
    int e = blockIdx.x * blockDim.x + threadIdx.x;
    if (e < E) {
        int d = dst[e];
        int p = off[d] + atomicAdd(&cur[d], 1);
        eid[p] = e;
    }
}

// ======== L1: fused edge-softmax + feature aggregation -> slim Acomb [N*4,256] ========
// 2-way edge unroll: two independent eid->src->el/feat load chains in flight.
__global__ __launch_bounds__(256) void aggregate_feat_sm(
    const int* __restrict__ off, const int* __restrict__ eid, const int* __restrict__ src,
    const float* __restrict__ el, const float* __restrict__ er,
    const short* __restrict__ featb, short* __restrict__ Acomb)
{
    int wv = threadIdx.x >> 6, lane = threadIdx.x & 63;
    int n = blockIdx.x * 4 + wv;
    int k4 = lane * 4;
    float4 erv = ((const float4*)er)[n];
    float acc[4][4] = {};
    float accd[4] = {};
    int beg = off[n], end = off[n + 1];
    int j = beg;
    for (; j + 1 < end; j += 2) {
        int e0 = eid[j], e1 = eid[j + 1];
        int s0 = src[e0], s1 = src[e1];
        float4 elv0 = ((const float4*)el)[s0];
        float4 elv1 = ((const float4*)el)[s1];
        short4v fv0 = *(const short4v*)(featb + (size_t)s0 * 256 + k4);
        short4v fv1 = *(const short4v*)(featb + (size_t)s1 * 256 + k4);
        float a[2][4];
        a[0][0] = elv0.x + erv.x; a[0][1] = elv0.y + erv.y; a[0][2] = elv0.z + erv.z; a[0][3] = elv0.w + erv.w;
        a[1][0] = elv1.x + erv.x; a[1][1] = elv1.y + erv.y; a[1][2] = elv1.z + erv.z; a[1][3] = elv1.w + erv.w;
#pragma unroll
        for (int u = 0; u < 2; u++)
#pragma unroll
            for (int h = 0; h < 4; h++) {
                float v = a[u][h];
                a[u][h] = __expf(v > 0.f ? v : 0.2f * v);
            }
        float f0[4] = { b2f(fv0[0]), b2f(fv0[1]), b2f(fv0[2]), b2f(fv0[3]) };
        float f1[4] = { b2f(fv1[0]), b2f(fv1[1]), b2f(fv1[2]), b2f(fv1[3]) };
#pragma unroll
        for (int h = 0; h < 4; h++) {
            accd[h] += a[0][h] + a[1][h];
#pragma unroll
            for (int kk = 0; kk < 4; kk++)
                acc[h][kk] = fmaf(a[1][h], f1[kk], fmaf(a[0][h], f0[kk], acc[h][kk]));
        }
    }
    if (j < end) {
        int e = eid[j];
        int s = src[e];
        float4 elv = ((const float4*)el)[s];
        float a0 = elv.x + erv.x, a1 = elv.y + erv.y, a2 = elv.z + erv.z, a3 = elv.w + erv.w;
        a0 = __expf(a0 > 0.f ? a0 : 0.2f * a0);
        a1 = __expf(a1 > 0.f ? a1 : 0.2f * a1);
        a2 = __expf(a2 > 0.f ? a2 : 0.2f * a2);
        a3 = __expf(a3 > 0.f ? a3 : 0.2f * a3);
        accd[0] += a0; accd[1] += a1; accd[2] += a2; accd[3] += a3;
        short4v fv = *(const short4v*)(featb + (size_t)s * 256 + k4);
        float f0 = b2f(fv[0]), f1 = b2f(fv[1]), f2 = b2f(fv[2]), f3 = b2f(fv[3]);
        acc[0][0] = fmaf(a0, f0, acc[0][0]); acc[0][1] = fmaf(a0, f1, acc[0][1]);
        acc[0][2] = fmaf(a0, f2, acc[0][2]); acc[0][3] = fmaf(a0, f3, acc[0][3]);
        acc[1][0] = fmaf(a1, f0, acc[1][0]); acc[1][1] = fmaf(a1, f1, acc[1][1]);
        acc[1][2] = fmaf(a1, f2, acc[1][2]); acc[1][3] = fmaf(a1, f3, acc[1][3]);
        acc[2][0] = fmaf(a2, f0, acc[2][0]); acc[2][1] = fmaf(a2, f1, acc[2][1]);
        acc[2][2] = fmaf(a2, f2, acc[2][2]); acc[2][3] = fmaf(a2, f3, acc[2][3]);
        acc[3][0] = fmaf(a3, f0, acc[3][0]); acc[3][1] = fmaf(a3, f1, acc[3][1]);
        acc[3][2] = fmaf(a3, f2, acc[3][2]); acc[3][3] = fmaf(a3, f3, acc[3][3]);
    }
    float inv[4];
#pragma unroll
    for (int h = 0; h < 4; h++) inv[h] = 1.f / (accd[h] == 0.f ? 1.f : accd[h]);
#pragma unroll
    for (int h = 0; h < 4; h++) {
        short4v o;
#pragma unroll
        for (int kk = 0; kk < 4; kk++) o[kk] = f2bf(acc[h][kk] * inv[h]);
        *(short4v*)(Acomb + ((size_t)n * 4 + h) * 256 + k4) = o;
    }
}

// ======== L2: fused edge-softmax + aggregation on z2res[M=N*4,256]=[z2|res2+b2] ========
// 2-way edge unroll for MLP.
__global__ __launch_bounds__(256) void aggregate2_sm(
    const int* __restrict__ off, const int* __restrict__ eid, const int* __restrict__ src,
    const float* __restrict__ el, const float* __restrict__ er,
    const short* __restrict__ z2res, short* __restrict__ h2)
{
    int n = blockIdx.x, t = threadIdx.x;
    int c = t >> 4;
    int p = t >> 6;
    int rem = (2 * t) & 127;
    float erv = er[n * 16 + c];
    float r0 = 0.f, r1 = 0.f, dn = 0.f;
    int beg = off[n], end = off[n + 1];
    int j = beg;
    for (; j + 1 < end; j += 2) {
        int e0 = eid[j], e1 = eid[j + 1];
        int s0 = src[e0], s1 = src[e1];
        float lv0 = el[s0 * 16 + c] + erv;
        float lv1 = el[s1 * 16 + c] + erv;
        unsigned zv0 = *(const unsigned*)(z2res + ((size_t)s0 * 4 + p) * 256 + rem);
        unsigned zv1 = *(const unsigned*)(z2res + ((size_t)s1 * 4 + p) * 256 + rem);
        float a0 = __expf(lv0 > 0.f ? lv0 : 0.2f * lv0);
        float a1 = __expf(lv1 > 0.f ? lv1 : 0.2f * lv1);
        dn += a0 + a1;
        r0 = fmaf(a1, b2f((short)(zv1 & 0xFFFFu)), fmaf(a0, b2f((short)(zv0 & 0xFFFFu)), r0));
        r1 = fmaf(a1, b2f((short)(zv1 >> 16)),     fmaf(a0, b2f((short)(zv0 >> 16)),     r1));
    }
    if (j < end) {
        int e = eid[j];
        int s = src[e];
        float lv = el[s * 16 + c] + erv;
        float a = __expf(lv > 0.f ? lv : 0.2f * lv);
        dn += a;
        unsigned zv = *(const unsigned*)(z2res + ((size_t)s * 4 + p) * 256 + rem);
        r0 = fmaf(a, b2f((short)(zv & 0xFFFFu)), r0);
        r1 = fmaf(a, b2f((short)(zv >> 16)), r1);
    }
    if (dn == 0.f) dn = 1.f;
    float inv = 1.f / dn;
    unsigned rv = *(const unsigned*)(z2res + ((size_t)n * 4 + p) * 256 + 128 + rem);
    float v0 = r0 * inv + b2f((short)(rv & 0xFFFFu));
    float v1 = r1 * inv + b2f((short)(rv >> 16));
    v0 = v0 > 0.f ? v0 : 0.f;
    v1 = v1 > 0.f ? v1 : 0.f;
    unsigned o = ((unsigned)(unsigned short)f2bf(v1) << 16) | (unsigned)(unsigned short)f2bf(v0);
    *(unsigned*)(h2 + (size_t)n * 512 + t * 2) = o;
}

// ======== launch ========
extern "C" void kernel_launch(void* const* d_in, const int* in_sizes, int n_in,
                              void* d_out, int out_size, void* d_ws, size_t ws_size,
                              hipStream_t stream)
{
    const float* feat  = (const float*)d_in[0];
    const int*   src   = (const int*)d_in[1];
    const int*   dst   = (const int*)d_in[2];
    const float* W1    = (const float*)d_in[3];
    const float* al1   = (const float*)d_in[4];
    const float* ar1   = (const float*)d_in[5];
    const float* resW1 = (const float*)d_in[6];
    const float* b1    = (const float*)d_in[7];
    const float* W2    = (const float*)d_in[8];
    const float* al2   = (const float*)d_in[9];
    const float* ar2   = (const float*)d_in[10];
    const float* resW2 = (const float*)d_in[11];
    const float* b2    = (const float*)d_in[12];
    const float* Wout  = (const float*)d_in[13];
    const float* bout  = (const float*)d_in[14];
    const int N = in_sizes[0] / IN_F;  // 8192
    const int E = in_sizes[1];         // 65536

    // ---- workspace layout (~80 MB) ----
    char* w = (char*)d_ws;
    auto alloc = [&](size_t bytes) -> char* {
        char* p = w;
        w += (bytes + 255) & ~(size_t)255;
        return p;
    };
    short*    Acomb   = (short*)alloc((size_t)N * 4 * 256 * 2);   // 16 MB (slim)
    short*    h1b     = (short*)alloc((size_t)N * 2048 * 2);      // 32 MB
    short*    featb   = (short*)alloc((size_t)N * 256 * 2);       // 4 MB
    short*    Wcomb   = (short*)alloc((size_t)2048 * 512 * 2);    // 2 MB
    short*    W2comb  = (short*)alloc((size_t)256 * 512 * 2);
    short*    Wtout   = (short*)alloc((size_t)128 * 512 * 2);
    float*    bias2c  = (float*)alloc((size_t)256 * 4);
    float*    wal1    = (float*)alloc((size_t)256 * 4 * 4);
    float*    war1    = (float*)alloc((size_t)256 * 4 * 4);
    float*    el1     = (float*)alloc((size_t)N * 4 * 4);
    float*    er1     = (float*)alloc((size_t)N * 4 * 4);
    int*      deg     = (int*)alloc((size_t)N * 4);               // deg+cur contiguous:
    int*      cur     = (int*)alloc((size_t)N * 4);               //   prep_all zeroes both
    int*      off     = (int*)alloc((size_t)(N + 1) * 4);
    int*      eid     = (int*)alloc((size_t)E * 4);
    short*    z2res   = (short*)alloc((size_t)N * 4 * 256 * 2);   // 16 MB
    short*    h2b     = (short*)alloc((size_t)N * 512 * 2);       // 8 MB
    float*    el2     = (float*)alloc((size_t)N * 16 * 4);
    float*    er2     = (float*)alloc((size_t)N * 16 * 4);

    dim3 blk(256);

    // ===== prep: fold1 + weight cvt + bias2c + zero(deg,cur) =====
    prep_all<<<dim3(1489), blk, 0, stream>>>(W1, al1, ar1, resW1, resW2, W2, Wout, b2,
                                             Wcomb, W2comb, Wtout,
                                             wal1, war1, bias2c, deg);

    // ===== front: feat cvt + el1/er1 + dst histogram (one dispatch) =====
    l1_front<<<dim3(N / 4 + E / 256), blk, 0, stream>>>(feat, (const float4*)wal1, (const float4*)war1,
                                                        featb, el1, er1, dst, deg, E, N / 4);
    scan_excl<<<dim3(1), dim3(1024), 0, stream>>>(deg, off, N);
    scatter_kernel<<<dim3((E + 255) / 256), blk, 0, stream>>>(dst, off, cur, eid, E);

    // ===== layer 1 =====
    aggregate_feat_sm<<<dim3(N / 4), blk, 0, stream>>>(off, eid, src, el1, er1, featb, Acomb);
    gemm_h1<<<dim3(4, N / 128, 4), blk, 0, stream>>>(Acomb, featb, Wcomb, b1, h1b);
    // h1b = bf16 h1 [N,4,512]

    // ===== layer 2 (GEMM with fused el2/er2 epilogue) =====
    gemm_bf16<<<dim3(2, (N * 4) / 128), blk, 0, stream>>>(h1b, W2comb, bias2c, z2res,
                                                          N * 4, 256, 512, 256, 256, 1,
                                                          el2, er2, al2, ar2, 1);
    aggregate2_sm<<<dim3(N), blk, 0, stream>>>(off, eid, src, el2, er2, z2res, h2b);
    // h2b = bf16 h2 [N,512]

    // ===== final linear =====
    gemm_bf16<<<dim3(1, N / 128), blk, 0, stream>>>(h2b, Wtout, bout, (float*)d_out,
                                                    N, 128, 512, 40, 40, 0,
                                                    nullptr, nullptr, nullptr, nullptr, 0);
}

// Round 14
// 125.201 us; speedup vs baseline: 1.2366x; 1.0783x over previous
//
#include <hip/hip_runtime.h>
#include <cmath>

constexpr int IN_F  = 256;

typedef short bf16x8 __attribute__((ext_vector_type(8)));
typedef short short4v __attribute__((ext_vector_type(4)));
typedef float f32x4 __attribute__((ext_vector_type(4)));

__device__ __forceinline__ short f2bf(float f) {
    unsigned u = __float_as_uint(f);
    unsigned r = (u + 0x7FFFu + ((u >> 16) & 1)) >> 16;  // RNE
    return (short)r;
}
__device__ __forceinline__ float b2f(short s) {
    return __uint_as_float(((unsigned)(unsigned short)s) << 16);
}

// ======== XCD-chunked block swizzle (T1) ========
__device__ __forceinline__ int xcd_logical_id()
{
    int nx = gridDim.x, ny = gridDim.y, nz = gridDim.z;
    int flat = blockIdx.x + nx * (blockIdx.y + ny * blockIdx.z);
    int nwg = nx * ny * nz;
    if (nwg & 7) return flat;
    int chunk = nwg >> 3;
    return (flat & 7) * chunk + (flat >> 3);
}

// ======== weight transpose to bf16 (device helper; 32x32 tile) ========
__device__ __forceinline__ void cvt_t_body(
    const float* __restrict__ W, short* __restrict__ Wt, int K, int N,
    int ldwt, int koff, int bk, int bn, int tx, int ty)
{
    __shared__ float tile[32][33];
    for (int i = ty; i < 32; i += 8) {
        int gn = bn + tx;
        tile[i][tx] = (gn < N) ? W[(size_t)(bk + i) * N + gn] : 0.f;
    }
    __syncthreads();
    for (int i = ty; i < 32; i += 8)
        Wt[(size_t)(bn + i) * ldwt + koff + bk + tx] = f2bf(tile[tx][i]);
}

// ======== mega prep kernel: fold1 + weight cvt + bias2c + zero(deg,cur) ========
__global__ __launch_bounds__(256) void prep_all(
    const float* __restrict__ W1, const float* __restrict__ al1, const float* __restrict__ ar1,
    const float* __restrict__ resW1, const float* __restrict__ resW2,
    const float* __restrict__ W2, const float* __restrict__ Wout, const float* __restrict__ b2,
    short* __restrict__ Wcomb, short* __restrict__ W2comb, short* __restrict__ Wtout,
    float* __restrict__ wal1, float* __restrict__ war1,
    float* __restrict__ bias2c, int* __restrict__ zero_base)
{
    int bid = blockIdx.x;
    int t   = threadIdx.x;
    if (bid < 256) {
        int wid  = (bid * 256 + t) >> 6;  // 0..1023
        int lane = t & 63;
        int k = wid >> 2, h = wid & 3;
        const float* wr  = W1  + (size_t)k * 2048 + h * 512;
        const float* alp = al1 + h * 512;
        const float* arp = ar1 + h * 512;
        float sl = 0.f, sr = 0.f;
        for (int j = lane; j < 512; j += 64) {
            float wv = wr[j];
            sl = fmaf(wv, alp[j], sl);
            sr = fmaf(wv, arp[j], sr);
        }
#pragma unroll
        for (int o = 32; o; o >>= 1) { sl += __shfl_down(sl, o); sr += __shfl_down(sr, o); }
        if (lane == 0) { wal1[wid] = sl; war1[wid] = sr; }
    } else if (bid < 1280) {
        int id = bid - 256;               // 1024 blocks: x=64, y=8, z=2
        int bx = id & 63, by = (id >> 6) & 7, bz = id >> 9;
        const float* W = bz ? resW1 : W1;
        cvt_t_body(W, Wcomb, 256, 2048, 512, bz ? 256 : 0,
                   by * 32, bx * 32, t & 31, t >> 5);
    } else if (bid < 1472) {
        int id = bid - 1280;              // 192 blocks: x=4, y=16, z=3
        int bx = id & 3, by = (id >> 2) & 15, bz = id >> 6;
        const float* W; short* Wt; int N;
        if (bz == 0)      { W = W2;    Wt = W2comb;             N = 128; }
        else if (bz == 1) { W = resW2; Wt = W2comb + 128 * 512; N = 128; }
        else              { W = Wout;  Wt = Wtout;              N = 40;  }
        cvt_t_body(W, Wt, 512, N, 512, 0, by * 32, bx * 32, t & 31, t >> 5);
    } else if (bid == 1472) {
        bias2c[t] = (t < 128) ? 0.f : b2[t - 128];
    } else {
        int b = bid - 1473;               // 16 blocks * 256 thr * 16B = 64KB
        int4 z; z.x = 0; z.y = 0; z.z = 0; z.w = 0;
        ((int4*)zero_base)[(size_t)b * 256 + t] = z;
    }
}

// ======== fused front: feat->bf16 + el1/er1 fold + dst histogram ========
__global__ __launch_bounds__(256) void l1_front(
    const float* __restrict__ feat, const float4* __restrict__ wal, const float4* __restrict__ war,
    short* __restrict__ featb, float* __restrict__ el, float* __restrict__ er,
    const int* __restrict__ dst, int* __restrict__ deg, int E, int nfeat)
{
    if ((int)blockIdx.x >= nfeat) {
        int e = (blockIdx.x - nfeat) * 256 + threadIdx.x;
        if (e < E) atomicAdd(&deg[dst[e]], 1);
        return;
    }
    int row  = blockIdx.x * 4 + (threadIdx.x >> 6);
    int lane = threadIdx.x & 63;
    float4 v = ((const float4*)feat)[(size_t)row * 64 + lane];
    short4v o;
    o[0] = f2bf(v.x); o[1] = f2bf(v.y); o[2] = f2bf(v.z); o[3] = f2bf(v.w);
    *(short4v*)(featb + (size_t)row * 256 + lane * 4) = o;

    float fj[4] = { v.x, v.y, v.z, v.w };
    int k = lane * 4;
    float sl[4] = {}, sr[4] = {};
#pragma unroll
    for (int j = 0; j < 4; j++) {
        float4 wl = wal[k + j], wr = war[k + j];
        sl[0] = fmaf(fj[j], wl.x, sl[0]); sl[1] = fmaf(fj[j], wl.y, sl[1]);
        sl[2] = fmaf(fj[j], wl.z, sl[2]); sl[3] = fmaf(fj[j], wl.w, sl[3]);
        sr[0] = fmaf(fj[j], wr.x, sr[0]); sr[1] = fmaf(fj[j], wr.y, sr[1]);
        sr[2] = fmaf(fj[j], wr.z, sr[2]); sr[3] = fmaf(fj[j], wr.w, sr[3]);
    }
#pragma unroll
    for (int o2 = 32; o2; o2 >>= 1) {
#pragma unroll
        for (int h = 0; h < 4; h++) { sl[h] += __shfl_down(sl[h], o2); sr[h] += __shfl_down(sr[h], o2); }
    }
    if (lane == 0) {
#pragma unroll
        for (int h = 0; h < 4; h++) { el[row * 4 + h] = sl[h]; er[row * 4 + h] = sr[h]; }
    }
}

// ======== bf16 MFMA GEMM, BK=64; fused el2/er2 epilogue on n0==0 tiles ========
__global__ __launch_bounds__(256) void gemm_bf16(
    const short* __restrict__ A, const short* __restrict__ Bt,
    const float* __restrict__ bias, void* __restrict__ C,
    int M, int N, int K, int ldc, int nmax, int out_bf16,
    float* __restrict__ el2, float* __restrict__ er2,
    const float* __restrict__ al2, const float* __restrict__ ar2, int do_el)
{
    __shared__ short sA[2][128 * 32];
    __shared__ short sB[2][128 * 32];
    const int tid  = threadIdx.x;
    const int wave = tid >> 6, lane = tid & 63;
    const int wm = wave >> 1, wn = wave & 1;
    int lid = xcd_logical_id();
    const int bx = lid % gridDim.x, by = lid / gridDim.x;
    const int m0 = by * 128, n0 = bx * 128;

    const int srow = tid >> 2;
    const int scol = (tid & 3) * 8;
    const int fr = lane & 15;
    const int fq = lane >> 4;

    f32x4 acc[4][4] = {};

    for (int k0 = 0; k0 < K; k0 += 64) {
#pragma unroll
        for (int hh = 0; hh < 2; hh++) {
            int kc = k0 + hh * 32 + scol;
            const short* ga0 = A  + (size_t)(m0 + srow) * K + kc;
            const short* ga1 = A  + (size_t)(m0 + 64 + srow) * K + kc;
            const short* gb0 = Bt + (size_t)(n0 + srow) * K + kc;
            const short* gb1 = Bt + (size_t)(n0 + 64 + srow) * K + kc;
            __builtin_amdgcn_global_load_lds((const __attribute__((address_space(1))) void*)ga0,
                (__attribute__((address_space(3))) void*)(sA[hh] + wave * 512), 16, 0, 0);
            __builtin_amdgcn_global_load_lds((const __attribute__((address_space(1))) void*)ga1,
                (__attribute__((address_space(3))) void*)(sA[hh] + 2048 + wave * 512), 16, 0, 0);
            __builtin_amdgcn_global_load_lds((const __attribute__((address_space(1))) void*)gb0,
                (__attribute__((address_space(3))) void*)(sB[hh] + wave * 512), 16, 0, 0);
            __builtin_amdgcn_global_load_lds((const __attribute__((address_space(1))) void*)gb1,
                (__attribute__((address_space(3))) void*)(sB[hh] + 2048 + wave * 512), 16, 0, 0);
        }
        __syncthreads();

#pragma unroll
        for (int hh = 0; hh < 2; hh++) {
            bf16x8 af[4], bfr[4];
#pragma unroll
            for (int m = 0; m < 4; m++)
                af[m] = *(const bf16x8*)(sA[hh] + (wm * 64 + m * 16 + fr) * 32 + fq * 8);
#pragma unroll
            for (int n = 0; n < 4; n++)
                bfr[n] = *(const bf16x8*)(sB[hh] + (wn * 64 + n * 16 + fr) * 32 + fq * 8);
#pragma unroll
            for (int m = 0; m < 4; m++)
#pragma unroll
                for (int n = 0; n < 4; n++)
                    acc[m][n] = __builtin_amdgcn_mfma_f32_16x16x32_bf16(af[m], bfr[n], acc[m][n], 0, 0, 0);
        }
        __syncthreads();
    }

    if (do_el && bx == 0) {
        float cal[4], car[4];
#pragma unroll
        for (int n = 0; n < 4; n++) {
            cal[n] = al2[wn * 64 + n * 16 + fr];
            car[n] = ar2[wn * 64 + n * 16 + fr];
        }
#pragma unroll
        for (int m = 0; m < 4; m++) {
#pragma unroll
            for (int j = 0; j < 4; j++) {
                float ell = acc[m][0][j] * cal[0] + acc[m][1][j] * cal[1];
                float elh = acc[m][2][j] * cal[2] + acc[m][3][j] * cal[3];
                float erl = acc[m][0][j] * car[0] + acc[m][1][j] * car[1];
                float erh = acc[m][2][j] * car[2] + acc[m][3][j] * car[3];
#pragma unroll
                for (int o = 1; o < 16; o <<= 1) {
                    ell += __shfl_xor(ell, o);
                    elh += __shfl_xor(elh, o);
                    erl += __shfl_xor(erl, o);
                    erh += __shfl_xor(erh, o);
                }
                if (fr == 0) {
                    int R = m0 + wm * 64 + m * 16 + fq * 4 + j;
                    el2[R * 4 + wn * 2]     = ell;
                    el2[R * 4 + wn * 2 + 1] = elh;
                    er2[R * 4 + wn * 2]     = erl;
                    er2[R * 4 + wn * 2 + 1] = erh;
                }
            }
        }
    }

#pragma unroll
    for (int n = 0; n < 4; n++) {
        int gcol = n0 + wn * 64 + n * 16 + fr;
        if (gcol >= nmax) continue;
        float bv = bias ? bias[gcol] : 0.f;
#pragma unroll
        for (int m = 0; m < 4; m++) {
#pragma unroll
            for (int j = 0; j < 4; j++) {
                int grow = m0 + wm * 64 + m * 16 + fq * 4 + j;
                float v = acc[m][n][j] + bv;
                if (out_bf16) ((short*)C)[(size_t)grow * ldc + gcol] = f2bf(v);
                else          ((float*)C)[(size_t)grow * ldc + gcol] = v;
            }
        }
    }
}

// ======== batched-by-head GEMM, BK=64: h1 = relu([agg|feat] @ [W1|resW1]_h^T + b1) ========
__global__ __launch_bounds__(256) void gemm_h1(
    const short* __restrict__ Acomb, const short* __restrict__ featb,
    const short* __restrict__ Wcomb, const float* __restrict__ b1, short* __restrict__ h1b)
{
    __shared__ short sA[2][128 * 32];
    __shared__ short sB[2][128 * 32];
    const int tid  = threadIdx.x;
    const int wave = tid >> 6, lane = tid & 63;
    const int wm = wave >> 1, wn = wave & 1;
    int lid = xcd_logical_id();                  // grid (4, M/128, 4)
    const int bx = lid & 3;
    const int by = (lid >> 2) % gridDim.y;
    const int h  = lid / (gridDim.y * 4);
    const int m0 = by * 128, n0 = bx * 128;
    const short* Bt = Wcomb + (size_t)(h * 512) * 512;

    const int srow = tid >> 2;
    const int scol = (tid & 3) * 8;
    const int fr = lane & 15;
    const int fq = lane >> 4;

    f32x4 acc[4][4] = {};

    for (int k0 = 0; k0 < 512; k0 += 64) {
        const int res_half = (k0 >= 256);
#pragma unroll
        for (int hh = 0; hh < 2; hh++) {
            int kc = k0 + hh * 32 + scol;
            const short* ga0;
            const short* ga1;
            if (!res_half) {
                ga0 = Acomb + ((size_t)(m0 + srow) * 4 + h) * 256 + kc;
                ga1 = Acomb + ((size_t)(m0 + 64 + srow) * 4 + h) * 256 + kc;
            } else {
                ga0 = featb + (size_t)(m0 + srow) * 256 + (kc - 256);
                ga1 = featb + (size_t)(m0 + 64 + srow) * 256 + (kc - 256);
            }
            const short* gb0 = Bt + (size_t)(n0 + srow) * 512 + kc;
            const short* gb1 = Bt + (size_t)(n0 + 64 + srow) * 512 + kc;
            __builtin_amdgcn_global_load_lds((const __attribute__((address_space(1))) void*)ga0,
                (__attribute__((address_space(3))) void*)(sA[hh] + wave * 512), 16, 0, 0);
            __builtin_amdgcn_global_load_lds((const __attribute__((address_space(1))) void*)ga1,
                (__attribute__((address_space(3))) void*)(sA[hh] + 2048 + wave * 512), 16, 0, 0);
            __builtin_amdgcn_global_load_lds((const __attribute__((address_space(1))) void*)gb0,
                (__attribute__((address_space(3))) void*)(sB[hh] + wave * 512), 16, 0, 0);
            __builtin_amdgcn_global_load_lds((const __attribute__((address_space(1))) void*)gb1,
                (__attribute__((address_space(3))) void*)(sB[hh] + 2048 + wave * 512), 16, 0, 0);
        }
        __syncthreads();

#pragma unroll
        for (int hh = 0; hh < 2; hh++) {
            bf16x8 af[4], bfr[4];
#pragma unroll
            for (int m = 0; m < 4; m++)
                af[m] = *(const bf16x8*)(sA[hh] + (wm * 64 + m * 16 + fr) * 32 + fq * 8);
#pragma unroll
            for (int n = 0; n < 4; n++)
                bfr[n] = *(const bf16x8*)(sB[hh] + (wn * 64 + n * 16 + fr) * 32 + fq * 8);
#pragma unroll
            for (int m = 0; m < 4; m++)
#pragma unroll
                for (int n = 0; n < 4; n++)
                    acc[m][n] = __builtin_amdgcn_mfma_f32_16x16x32_bf16(af[m], bfr[n], acc[m][n], 0, 0, 0);
        }
        __syncthreads();
    }

#pragma unroll
    for (int n = 0; n < 4; n++) {
        int gcol = h * 512 + n0 + wn * 64 + n * 16 + fr;
        float bv = b1[gcol];
#pragma unroll
        for (int m = 0; m < 4; m++) {
#pragma unroll
            for (int j = 0; j < 4; j++) {
                int grow = m0 + wm * 64 + m * 16 + fq * 4 + j;
                float v = acc[m][n][j] + bv;
                h1b[(size_t)grow * 2048 + gcol] = f2bf(v > 0.f ? v : 0.f);
            }
        }
    }
}

// ======== final thin GEMM: out[M,40] = h2[M,512] @ Wtout^T + bout ========
// 64x64 tile, 4 waves (2x2 of 32x32), grid = M/64 blocks (128): 2x parallelism,
// half the zero-col MFMA waste vs the 128x128 path.
__global__ __launch_bounds__(256) void gemm_final(
    const short* __restrict__ A, const short* __restrict__ Bt,
    const float* __restrict__ bias, float* __restrict__ C)
{
    __shared__ short sA[2][64 * 32];
    __shared__ short sB[2][64 * 32];
    const int tid  = threadIdx.x;
    const int wave = tid >> 6, lane = tid & 63;
    const int wm = wave >> 1, wn = wave & 1;
    int lid = xcd_logical_id();          // 1-D grid, %8==0
    const int m0 = lid * 64;

    const int srow = tid >> 2;           // 0..63
    const int scol = (tid & 3) * 8;
    const int fr = lane & 15;
    const int fq = lane >> 4;

    f32x4 acc[2][2] = {};

    for (int k0 = 0; k0 < 512; k0 += 64) {
#pragma unroll
        for (int hh = 0; hh < 2; hh++) {
            int kc = k0 + hh * 32 + scol;
            const short* ga = A  + (size_t)(m0 + srow) * 512 + kc;
            const short* gb = Bt + (size_t)srow * 512 + kc;      // outcols 0..63
            __builtin_amdgcn_global_load_lds((const __attribute__((address_space(1))) void*)ga,
                (__attribute__((address_space(3))) void*)(sA[hh] + wave * 512), 16, 0, 0);
            __builtin_amdgcn_global_load_lds((const __attribute__((address_space(1))) void*)gb,
                (__attribute__((address_space(3))) void*)(sB[hh] + wave * 512), 16, 0, 0);
        }
        __syncthreads();

#pragma unroll
        for (int hh = 0; hh < 2; hh++) {
            bf16x8 af[2], bfr[2];
#pragma unroll
            for (int m = 0; m < 2; m++)
                af[m] = *(const bf16x8*)(sA[hh] + (wm * 32 + m * 16 + fr) * 32 + fq * 8);
#pragma unroll
            for (int n = 0; n < 2; n++)
                bfr[n] = *(const bf16x8*)(sB[hh] + (wn * 32 + n * 16 + fr) * 32 + fq * 8);
#pragma unroll
            for (int m = 0; m < 2; m++)
#pragma unroll
                for (int n = 0; n < 2; n++)
                    acc[m][n] = __builtin_amdgcn_mfma_f32_16x16x32_bf16(af[m], bfr[n], acc[m][n], 0, 0, 0);
        }
        __syncthreads();
    }

#pragma unroll
    for (int n = 0; n < 2; n++) {
        int gcol = wn * 32 + n * 16 + fr;
        if (gcol >= 40) continue;
        float bv = bias[gcol];
#pragma unroll
        for (int m = 0; m < 2; m++) {
#pragma unroll
            for (int j = 0; j < 4; j++) {
                int grow = m0 + wm * 32 + m * 16 + fq * 4 + j;
                C[(size_t)grow * 40 + gcol] = acc[m][n][j] + bv;
            }
        }
    }
}

// ======== CSR scan + scatter ========
__global__ __launch_bounds__(1024) void scan_excl(const int* __restrict__ deg,
                                                  int* __restrict__ off, int N)
{
    __shared__ int part[1024];
    int t = threadIdx.x;
    int chunk = N >> 10;
    int base = t * chunk;
    int local[16];
    int s = 0;
    for (int i = 0; i < chunk; i++) { local[i] = s; s += deg[base + i]; }
    part[t] = s;
    __syncthreads();
    for (int o = 1; o < 1024; o <<= 1) {
        int v = (t >= o) ? part[t - o] : 0;
        __syncthreads();
        part[t] += v;
        __syncthreads();
    }
    int pre = (t == 0) ? 0 : part[t - 1];
    for (int i = 0; i < chunk; i++) off[base + i] = pre + local[i];
    if (t == 1023) off[N] = pre + s;
}

__global__ void scatter_kernel(const int* __restrict__ dst, const int* __restrict__ off,
                               int* __restrict__ cur, int* __restrict__ eid, int E)
{
    int e = blockIdx.x * blockDim.x + threadIdx.x;
    if (e < E) {
        int d = dst[e];
        int p = off[d] + atomicAdd(&cur[d], 1);
        eid[p] = e;
    }
}

// ======== L1: fused edge-softmax + feature aggregation -> slim Acomb [N*4,256] ========
// 4-way edge unroll: four independent eid->src->el/feat load chains in flight.
__global__ __launch_bounds__(256) void aggregate_feat_sm(
    const int* __restrict__ off, const int* __restrict__ eid, const int* __restrict__ src,
    const float* __restrict__ el, const float* __restrict__ er,
    const short* __restrict__ featb, short* __restrict__ Acomb)
{
    int wv = threadIdx.x >> 6, lane = threadIdx.x & 63;
    int n = blockIdx.x * 4 + wv;
    int k4 = lane * 4;
    float4 erv = ((const float4*)er)[n];
    float acc[4][4] = {};
    float accd[4] = {};
    int beg = off[n], end = off[n + 1];
    int j = beg;
    for (; j + 3 < end; j += 4) {
        int e0 = eid[j], e1 = eid[j + 1], e2 = eid[j + 2], e3 = eid[j + 3];
        int s0 = src[e0], s1 = src[e1], s2 = src[e2], s3 = src[e3];
        float4 elv0 = ((const float4*)el)[s0];
        float4 elv1 = ((const float4*)el)[s1];
        float4 elv2 = ((const float4*)el)[s2];
        float4 elv3 = ((const float4*)el)[s3];
        short4v fv0 = *(const short4v*)(featb + (size_t)s0 * 256 + k4);
        short4v fv1 = *(const short4v*)(featb + (size_t)s1 * 256 + k4);
        short4v fv2 = *(const short4v*)(featb + (size_t)s2 * 256 + k4);
        short4v fv3 = *(const short4v*)(featb + (size_t)s3 * 256 + k4);
        float a[4][4];
        a[0][0] = elv0.x + erv.x; a[0][1] = elv0.y + erv.y; a[0][2] = elv0.z + erv.z; a[0][3] = elv0.w + erv.w;
        a[1][0] = elv1.x + erv.x; a[1][1] = elv1.y + erv.y; a[1][2] = elv1.z + erv.z; a[1][3] = elv1.w + erv.w;
        a[2][0] = elv2.x + erv.x; a[2][1] = elv2.y + erv.y; a[2][2] = elv2.z + erv.z; a[2][3] = elv2.w + erv.w;
        a[3][0] = elv3.x + erv.x; a[3][1] = elv3.y + erv.y; a[3][2] = elv3.z + erv.z; a[3][3] = elv3.w + erv.w;
#pragma unroll
        for (int u = 0; u < 4; u++)
#pragma unroll
            for (int h = 0; h < 4; h++) {
                float v = a[u][h];
                a[u][h] = __expf(v > 0.f ? v : 0.2f * v);
            }
        float f0[4] = { b2f(fv0[0]), b2f(fv0[1]), b2f(fv0[2]), b2f(fv0[3]) };
        float f1[4] = { b2f(fv1[0]), b2f(fv1[1]), b2f(fv1[2]), b2f(fv1[3]) };
        float f2[4] = { b2f(fv2[0]), b2f(fv2[1]), b2f(fv2[2]), b2f(fv2[3]) };
        float f3[4] = { b2f(fv3[0]), b2f(fv3[1]), b2f(fv3[2]), b2f(fv3[3]) };
#pragma unroll
        for (int h = 0; h < 4; h++) {
            accd[h] += (a[0][h] + a[1][h]) + (a[2][h] + a[3][h]);
#pragma unroll
            for (int kk = 0; kk < 4; kk++) {
                float t0 = fmaf(a[1][h], f1[kk], fmaf(a[0][h], f0[kk], acc[h][kk]));
                acc[h][kk] = fmaf(a[3][h], f3[kk], fmaf(a[2][h], f2[kk], t0));
            }
        }
    }
    for (; j < end; ++j) {
        int e = eid[j];
        int s = src[e];
        float4 elv = ((const float4*)el)[s];
        float a0 = elv.x + erv.x, a1 = elv.y + erv.y, a2 = elv.z + erv.z, a3 = elv.w + erv.w;
        a0 = __expf(a0 > 0.f ? a0 : 0.2f * a0);
        a1 = __expf(a1 > 0.f ? a1 : 0.2f * a1);
        a2 = __expf(a2 > 0.f ? a2 : 0.2f * a2);
        a3 = __expf(a3 > 0.f ? a3 : 0.2f * a3);
        accd[0] += a0; accd[1] += a1; accd[2] += a2; accd[3] += a3;
        short4v fv = *(const short4v*)(featb + (size_t)s * 256 + k4);
        float f0 = b2f(fv[0]), f1 = b2f(fv[1]), f2 = b2f(fv[2]), f3 = b2f(fv[3]);
        acc[0][0] = fmaf(a0, f0, acc[0][0]); acc[0][1] = fmaf(a0, f1, acc[0][1]);
        acc[0][2] = fmaf(a0, f2, acc[0][2]); acc[0][3] = fmaf(a0, f3, acc[0][3]);
        acc[1][0] = fmaf(a1, f0, acc[1][0]); acc[1][1] = fmaf(a1, f1, acc[1][1]);
        acc[1][2] = fmaf(a1, f2, acc[1][2]); acc[1][3] = fmaf(a1, f3, acc[1][3]);
        acc[2][0] = fmaf(a2, f0, acc[2][0]); acc[2][1] = fmaf(a2, f1, acc[2][1]);
        acc[2][2] = fmaf(a2, f2, acc[2][2]); acc[2][3] = fmaf(a2, f3, acc[2][3]);
        acc[3][0] = fmaf(a3, f0, acc[3][0]); acc[3][1] = fmaf(a3, f1, acc[3][1]);
        acc[3][2] = fmaf(a3, f2, acc[3][2]); acc[3][3] = fmaf(a3, f3, acc[3][3]);
    }
    float inv[4];
#pragma unroll
    for (int h = 0; h < 4; h++) inv[h] = 1.f / (accd[h] == 0.f ? 1.f : accd[h]);
#pragma unroll
    for (int h = 0; h < 4; h++) {
        short4v o;
#pragma unroll
        for (int kk = 0; kk < 4; kk++) o[kk] = f2bf(acc[h][kk] * inv[h]);
        *(short4v*)(Acomb + ((size_t)n * 4 + h) * 256 + k4) = o;
    }
}

// ======== L2: fused edge-softmax + aggregation on z2res[M=N*4,256]=[z2|res2+b2] ========
// 4-way edge unroll; residual load hoisted above the loop.
__global__ __launch_bounds__(256) void aggregate2_sm(
    const int* __restrict__ off, const int* __restrict__ eid, const int* __restrict__ src,
    const float* __restrict__ el, const float* __restrict__ er,
    const short* __restrict__ z2res, short* __restrict__ h2)
{
    int n = blockIdx.x, t = threadIdx.x;
    int c = t >> 4;
    int p = t >> 6;
    int rem = (2 * t) & 127;
    float erv = er[n * 16 + c];
    unsigned rv = *(const unsigned*)(z2res + ((size_t)n * 4 + p) * 256 + 128 + rem);
    float r0 = 0.f, r1 = 0.f, dn = 0.f;
    int beg = off[n], end = off[n + 1];
    int j = beg;
    for (; j + 3 < end; j += 4) {
        int e0 = eid[j], e1 = eid[j + 1], e2 = eid[j + 2], e3 = eid[j + 3];
        int s0 = src[e0], s1 = src[e1], s2 = src[e2], s3 = src[e3];
        float lv0 = el[s0 * 16 + c] + erv;
        float lv1 = el[s1 * 16 + c] + erv;
        float lv2 = el[s2 * 16 + c] + erv;
        float lv3 = el[s3 * 16 + c] + erv;
        unsigned zv0 = *(const unsigned*)(z2res + ((size_t)s0 * 4 + p) * 256 + rem);
        unsigned zv1 = *(const unsigned*)(z2res + ((size_t)s1 * 4 + p) * 256 + rem);
        unsigned zv2 = *(const unsigned*)(z2res + ((size_t)s2 * 4 + p) * 256 + rem);
        unsigned zv3 = *(const unsigned*)(z2res + ((size_t)s3 * 4 + p) * 256 + rem);
        float a0 = __expf(lv0 > 0.f ? lv0 : 0.2f * lv0);
        float a1 = __expf(lv1 > 0.f ? lv1 : 0.2f * lv1);
        float a2 = __expf(lv2 > 0.f ? lv2 : 0.2f * lv2);
        float a3 = __expf(lv3 > 0.f ? lv3 : 0.2f * lv3);
        dn += (a0 + a1) + (a2 + a3);
        float t0 = fmaf(a1, b2f((short)(zv1 & 0xFFFFu)), fmaf(a0, b2f((short)(zv0 & 0xFFFFu)), r0));
        r0 = fmaf(a3, b2f((short)(zv3 & 0xFFFFu)), fmaf(a2, b2f((short)(zv2 & 0xFFFFu)), t0));
        float t1 = fmaf(a1, b2f((short)(zv1 >> 16)), fmaf(a0, b2f((short)(zv0 >> 16)), r1));
        r1 = fmaf(a3, b2f((short)(zv3 >> 16)), fmaf(a2, b2f((short)(zv2 >> 16)), t1));
    }
    for (; j < end; ++j) {
        int e = eid[j];
        int s = src[e];
        float lv = el[s * 16 + c] + erv;
        float a = __expf(lv > 0.f ? lv : 0.2f * lv);
        dn += a;
        unsigned zv = *(const unsigned*)(z2res + ((size_t)s * 4 + p) * 256 + rem);
        r0 = fmaf(a, b2f((short)(zv & 0xFFFFu)), r0);
        r1 = fmaf(a, b2f((short)(zv >> 16)), r1);
    }
    if (dn == 0.f) dn = 1.f;
    float inv = 1.f / dn;
    float v0 = r0 * inv + b2f((short)(rv & 0xFFFFu));
    float v1 = r1 * inv + b2f((short)(rv >> 16));
    v0 = v0 > 0.f ? v0 : 0.f;
    v1 = v1 > 0.f ? v1 : 0.f;
    unsigned o = ((unsigned)(unsigned short)f2bf(v1) << 16) | (unsigned)(unsigned short)f2bf(v0);
    *(unsigned*)(h2 + (size_t)n * 512 + t * 2) = o;
}

// ======== launch ========
extern "C" void kernel_launch(void* const* d_in, const int* in_sizes, int n_in,
                              void* d_out, int out_size, void* d_ws, size_t ws_size,
                              hipStream_t stream)
{
    const float* feat  = (const float*)d_in[0];
    const int*   src   = (const int*)d_in[1];
    const int*   dst   = (const int*)d_in[2];
    const float* W1    = (const float*)d_in[3];
    const float* al1   = (const float*)d_in[4];
    const float* ar1   = (const float*)d_in[5];
    const float* resW1 = (const float*)d_in[6];
    const float* b1    = (const float*)d_in[7];
    const float* W2    = (const float*)d_in[8];
    const float* al2   = (const float*)d_in[9];
    const float* ar2   = (const float*)d_in[10];
    const float* resW2 = (const float*)d_in[11];
    const float* b2    = (const float*)d_in[12];
    const float* Wout  = (const float*)d_in[13];
    const float* bout  = (const float*)d_in[14];
    const int N = in_sizes[0] / IN_F;  // 8192
    const int E = in_sizes[1];         // 65536

    // ---- workspace layout (~80 MB) ----
    char* w = (char*)d_ws;
    auto alloc = [&](size_t bytes) -> char* {
        char* p = w;
        w += (bytes + 255) & ~(size_t)255;
        return p;
    };
    short*    Acomb   = (short*)alloc((size_t)N * 4 * 256 * 2);   // 16 MB (slim)
    short*    h1b     = (short*)alloc((size_t)N * 2048 * 2);      // 32 MB
    short*    featb   = (short*)alloc((size_t)N * 256 * 2);       // 4 MB
    short*    Wcomb   = (short*)alloc((size_t)2048 * 512 * 2);    // 2 MB
    short*    W2comb  = (short*)alloc((size_t)256 * 512 * 2);
    short*    Wtout   = (short*)alloc((size_t)128 * 512 * 2);
    float*    bias2c  = (float*)alloc((size_t)256 * 4);
    float*    wal1    = (float*)alloc((size_t)256 * 4 * 4);
    float*    war1    = (float*)alloc((size_t)256 * 4 * 4);
    float*    el1     = (float*)alloc((size_t)N * 4 * 4);
    float*    er1     = (float*)alloc((size_t)N * 4 * 4);
    int*      deg     = (int*)alloc((size_t)N * 4);               // deg+cur contiguous:
    int*      cur     = (int*)alloc((size_t)N * 4);               //   prep_all zeroes both
    int*      off     = (int*)alloc((size_t)(N + 1) * 4);
    int*      eid     = (int*)alloc((size_t)E * 4);
    short*    z2res   = (short*)alloc((size_t)N * 4 * 256 * 2);   // 16 MB
    short*    h2b     = (short*)alloc((size_t)N * 512 * 2);       // 8 MB
    float*    el2     = (float*)alloc((size_t)N * 16 * 4);
    float*    er2     = (float*)alloc((size_t)N * 16 * 4);

    dim3 blk(256);

    // ===== prep: fold1 + weight cvt + bias2c + zero(deg,cur) =====
    prep_all<<<dim3(1489), blk, 0, stream>>>(W1, al1, ar1, resW1, resW2, W2, Wout, b2,
                                             Wcomb, W2comb, Wtout,
                                             wal1, war1, bias2c, deg);

    // ===== front: feat cvt + el1/er1 + dst histogram (one dispatch) =====
    l1_front<<<dim3(N / 4 + E / 256), blk, 0, stream>>>(feat, (const float4*)wal1, (const float4*)war1,
                                                        featb, el1, er1, dst, deg, E, N / 4);
    scan_excl<<<dim3(1), dim3(1024), 0, stream>>>(deg, off, N);
    scatter_kernel<<<dim3((E + 255) / 256), blk, 0, stream>>>(dst, off, cur, eid, E);

    // ===== layer 1 =====
    aggregate_feat_sm<<<dim3(N / 4), blk, 0, stream>>>(off, eid, src, el1, er1, featb, Acomb);
    gemm_h1<<<dim3(4, N / 128, 4), blk, 0, stream>>>(Acomb, featb, Wcomb, b1, h1b);
    // h1b = bf16 h1 [N,4,512]

    // ===== layer 2 (GEMM with fused el2/er2 epilogue) =====
    gemm_bf16<<<dim3(2, (N * 4) / 128), blk, 0, stream>>>(h1b, W2comb, bias2c, z2res,
                                                          N * 4, 256, 512, 256, 256, 1,
                                                          el2, er2, al2, ar2, 1);
    aggregate2_sm<<<dim3(N), blk, 0, stream>>>(off, eid, src, el2, er2, z2res, h2b);
    // h2b = bf16 h2 [N,512]

    // ===== final linear (64x64 tile, 128 blocks) =====
    gemm_final<<<dim3(N / 64), blk, 0, stream>>>(h2b, Wtout, bout, (float*)d_out);
}

// Round 15
// 122.959 us; speedup vs baseline: 1.2591x; 1.0182x over previous
//
#include <hip/hip_runtime.h>
#include <cmath>

constexpr int IN_F  = 256;

typedef short bf16x8 __attribute__((ext_vector_type(8)));
typedef short short4v __attribute__((ext_vector_type(4)));
typedef float f32x4 __attribute__((ext_vector_type(4)));

__device__ __forceinline__ short f2bf(float f) {
    unsigned u = __float_as_uint(f);
    unsigned r = (u + 0x7FFFu + ((u >> 16) & 1)) >> 16;  // RNE
    return (short)r;
}
__device__ __forceinline__ float b2f(short s) {
    return __uint_as_float(((unsigned)(unsigned short)s) << 16);
}

// ======== XCD-chunked block swizzle (T1) ========
__device__ __forceinline__ int xcd_logical_id()
{
    int nx = gridDim.x, ny = gridDim.y, nz = gridDim.z;
    int flat = blockIdx.x + nx * (blockIdx.y + ny * blockIdx.z);
    int nwg = nx * ny * nz;
    if (nwg & 7) return flat;
    int chunk = nwg >> 3;
    return (flat & 7) * chunk + (flat >> 3);
}

// ======== weight transpose to bf16 (device helper; 32x32 tile) ========
__device__ __forceinline__ void cvt_t_body(
    const float* __restrict__ W, short* __restrict__ Wt, int K, int N,
    int ldwt, int koff, int bk, int bn, int tx, int ty)
{
    __shared__ float tile[32][33];
    for (int i = ty; i < 32; i += 8) {
        int gn = bn + tx;
        tile[i][tx] = (gn < N) ? W[(size_t)(bk + i) * N + gn] : 0.f;
    }
    __syncthreads();
    for (int i = ty; i < 32; i += 8)
        Wt[(size_t)(bn + i) * ldwt + koff + bk + tx] = f2bf(tile[tx][i]);
}

// ======== mega prep kernel: fold1 + weight cvt + bias2c + zero(deg,cur) ========
__global__ __launch_bounds__(256) void prep_all(
    const float* __restrict__ W1, const float* __restrict__ al1, const float* __restrict__ ar1,
    const float* __restrict__ resW1, const float* __restrict__ resW2,
    const float* __restrict__ W2, const float* __restrict__ Wout, const float* __restrict__ b2,
    short* __restrict__ Wcomb, short* __restrict__ W2comb, short* __restrict__ Wtout,
    float* __restrict__ wal1, float* __restrict__ war1,
    float* __restrict__ bias2c, int* __restrict__ zero_base)
{
    int bid = blockIdx.x;
    int t   = threadIdx.x;
    if (bid < 256) {
        int wid  = (bid * 256 + t) >> 6;  // 0..1023
        int lane = t & 63;
        int k = wid >> 2, h = wid & 3;
        const float* wr  = W1  + (size_t)k * 2048 + h * 512;
        const float* alp = al1 + h * 512;
        const float* arp = ar1 + h * 512;
        float sl = 0.f, sr = 0.f;
        for (int j = lane; j < 512; j += 64) {
            float wv = wr[j];
            sl = fmaf(wv, alp[j], sl);
            sr = fmaf(wv, arp[j], sr);
        }
#pragma unroll
        for (int o = 32; o; o >>= 1) { sl += __shfl_down(sl, o); sr += __shfl_down(sr, o); }
        if (lane == 0) { wal1[wid] = sl; war1[wid] = sr; }
    } else if (bid < 1280) {
        int id = bid - 256;               // 1024 blocks: x=64, y=8, z=2
        int bx = id & 63, by = (id >> 6) & 7, bz = id >> 9;
        const float* W = bz ? resW1 : W1;
        cvt_t_body(W, Wcomb, 256, 2048, 512, bz ? 256 : 0,
                   by * 32, bx * 32, t & 31, t >> 5);
    } else if (bid < 1472) {
        int id = bid - 1280;              // 192 blocks: x=4, y=16, z=3
        int bx = id & 3, by = (id >> 2) & 15, bz = id >> 6;
        const float* W; short* Wt; int N;
        if (bz == 0)      { W = W2;    Wt = W2comb;             N = 128; }
        else if (bz == 1) { W = resW2; Wt = W2comb + 128 * 512; N = 128; }
        else              { W = Wout;  Wt = Wtout;              N = 40;  }
        cvt_t_body(W, Wt, 512, N, 512, 0, by * 32, bx * 32, t & 31, t >> 5);
    } else if (bid == 1472) {
        bias2c[t] = (t < 128) ? 0.f : b2[t - 128];
    } else {
        int b = bid - 1473;               // 16 blocks * 256 thr * 16B = 64KB
        int4 z; z.x = 0; z.y = 0; z.z = 0; z.w = 0;
        ((int4*)zero_base)[(size_t)b * 256 + t] = z;
    }
}

// ======== fused front: feat->bf16 + el1/er1 fold + dst histogram ========
__global__ __launch_bounds__(256) void l1_front(
    const float* __restrict__ feat, const float4* __restrict__ wal, const float4* __restrict__ war,
    short* __restrict__ featb, float* __restrict__ el, float* __restrict__ er,
    const int* __restrict__ dst, int* __restrict__ deg, int E, int nfeat)
{
    if ((int)blockIdx.x >= nfeat) {
        int e = (blockIdx.x - nfeat) * 256 + threadIdx.x;
        if (e < E) atomicAdd(&deg[dst[e]], 1);
        return;
    }
    int row  = blockIdx.x * 4 + (threadIdx.x >> 6);
    int lane = threadIdx.x & 63;
    float4 v = ((const float4*)feat)[(size_t)row * 64 + lane];
    short4v o;
    o[0] = f2bf(v.x); o[1] = f2bf(v.y); o[2] = f2bf(v.z); o[3] = f2bf(v.w);
    *(short4v*)(featb + (size_t)row * 256 + lane * 4) = o;

    float fj[4] = { v.x, v.y, v.z, v.w };
    int k = lane * 4;
    float sl[4] = {}, sr[4] = {};
#pragma unroll
    for (int j = 0; j < 4; j++) {
        float4 wl = wal[k + j], wr = war[k + j];
        sl[0] = fmaf(fj[j], wl.x, sl[0]); sl[1] = fmaf(fj[j], wl.y, sl[1]);
        sl[2] = fmaf(fj[j], wl.z, sl[2]); sl[3] = fmaf(fj[j], wl.w, sl[3]);
        sr[0] = fmaf(fj[j], wr.x, sr[0]); sr[1] = fmaf(fj[j], wr.y, sr[1]);
        sr[2] = fmaf(fj[j], wr.z, sr[2]); sr[3] = fmaf(fj[j], wr.w, sr[3]);
    }
#pragma unroll
    for (int o2 = 32; o2; o2 >>= 1) {
#pragma unroll
        for (int h = 0; h < 4; h++) { sl[h] += __shfl_down(sl[h], o2); sr[h] += __shfl_down(sr[h], o2); }
    }
    if (lane == 0) {
#pragma unroll
        for (int h = 0; h < 4; h++) { el[row * 4 + h] = sl[h]; er[row * 4 + h] = sr[h]; }
    }
}

// ======== staging + MFMA helpers (BK=64, 128x128 tile, 4 waves) ========
__device__ __forceinline__ void stage_pair(
    const short* ga0, const short* ga1, const short* gb0, const short* gb1,
    short* sa, short* sb, int wave)
{
    __builtin_amdgcn_global_load_lds((const __attribute__((address_space(1))) void*)ga0,
        (__attribute__((address_space(3))) void*)(sa + wave * 512), 16, 0, 0);
    __builtin_amdgcn_global_load_lds((const __attribute__((address_space(1))) void*)ga1,
        (__attribute__((address_space(3))) void*)(sa + 2048 + wave * 512), 16, 0, 0);
    __builtin_amdgcn_global_load_lds((const __attribute__((address_space(1))) void*)gb0,
        (__attribute__((address_space(3))) void*)(sb + wave * 512), 16, 0, 0);
    __builtin_amdgcn_global_load_lds((const __attribute__((address_space(1))) void*)gb1,
        (__attribute__((address_space(3))) void*)(sb + 2048 + wave * 512), 16, 0, 0);
}

__device__ __forceinline__ void mfma_step(
    const short* sa, const short* sb, int wm, int wn, int fr, int fq, f32x4 acc[4][4])
{
    bf16x8 af[4], bfr[4];
#pragma unroll
    for (int m = 0; m < 4; m++)
        af[m] = *(const bf16x8*)(sa + (wm * 64 + m * 16 + fr) * 32 + fq * 8);
#pragma unroll
    for (int n = 0; n < 4; n++)
        bfr[n] = *(const bf16x8*)(sb + (wn * 64 + n * 16 + fr) * 32 + fq * 8);
#pragma unroll
    for (int m = 0; m < 4; m++)
#pragma unroll
        for (int n = 0; n < 4; n++)
            acc[m][n] = __builtin_amdgcn_mfma_f32_16x16x32_bf16(af[m], bfr[n], acc[m][n], 0, 0, 0);
}

// ======== layer-2 GEMM (specialized): z2res[M,256] = h1[M,512] @ W2comb^T + bias2c ========
// K=512, N=256 compile-time; fused el2/er2 epilogue on bx==0 tiles.
__global__ __launch_bounds__(256) void gemm_l2(
    const short* __restrict__ A, const short* __restrict__ Bt,
    const float* __restrict__ bias, short* __restrict__ C,
    float* __restrict__ el2, float* __restrict__ er2,
    const float* __restrict__ al2, const float* __restrict__ ar2)
{
    __shared__ short sA[2][128 * 32];
    __shared__ short sB[2][128 * 32];
    const int tid  = threadIdx.x;
    const int wave = tid >> 6, lane = tid & 63;
    const int wm = wave >> 1, wn = wave & 1;
    int lid = xcd_logical_id();          // grid (2, M/128)
    const int bx = lid & 1, by = lid >> 1;
    const int m0 = by * 128, n0 = bx * 128;

    const int srow = tid >> 2;
    const int scol = (tid & 3) * 8;
    const int fr = lane & 15;
    const int fq = lane >> 4;

    f32x4 acc[4][4] = {};

#pragma unroll 2
    for (int k0 = 0; k0 < 512; k0 += 64) {
#pragma unroll
        for (int hh = 0; hh < 2; hh++) {
            int kc = k0 + hh * 32 + scol;
            stage_pair(A  + (size_t)(m0 + srow) * 512 + kc,
                       A  + (size_t)(m0 + 64 + srow) * 512 + kc,
                       Bt + (size_t)(n0 + srow) * 512 + kc,
                       Bt + (size_t)(n0 + 64 + srow) * 512 + kc,
                       sA[hh], sB[hh], wave);
        }
        __syncthreads();
#pragma unroll
        for (int hh = 0; hh < 2; hh++)
            mfma_step(sA[hh], sB[hh], wm, wn, fr, fq, acc);
        __syncthreads();
    }

    // fused el2/er2: z2-tiles (bx==0) hold all 128 z2 cols in acc
    if (bx == 0) {
        float cal[4], car[4];
#pragma unroll
        for (int n = 0; n < 4; n++) {
            cal[n] = al2[wn * 64 + n * 16 + fr];
            car[n] = ar2[wn * 64 + n * 16 + fr];
        }
#pragma unroll
        for (int m = 0; m < 4; m++) {
#pragma unroll
            for (int j = 0; j < 4; j++) {
                float ell = acc[m][0][j] * cal[0] + acc[m][1][j] * cal[1];
                float elh = acc[m][2][j] * cal[2] + acc[m][3][j] * cal[3];
                float erl = acc[m][0][j] * car[0] + acc[m][1][j] * car[1];
                float erh = acc[m][2][j] * car[2] + acc[m][3][j] * car[3];
#pragma unroll
                for (int o = 1; o < 16; o <<= 1) {
                    ell += __shfl_xor(ell, o);
                    elh += __shfl_xor(elh, o);
                    erl += __shfl_xor(erl, o);
                    erh += __shfl_xor(erh, o);
                }
                if (fr == 0) {
                    int R = m0 + wm * 64 + m * 16 + fq * 4 + j;
                    el2[R * 4 + wn * 2]     = ell;
                    el2[R * 4 + wn * 2 + 1] = elh;
                    er2[R * 4 + wn * 2]     = erl;
                    er2[R * 4 + wn * 2 + 1] = erh;
                }
            }
        }
    }

#pragma unroll
    for (int n = 0; n < 4; n++) {
        int gcol = n0 + wn * 64 + n * 16 + fr;
        float bv = bias[gcol];
#pragma unroll
        for (int m = 0; m < 4; m++) {
#pragma unroll
            for (int j = 0; j < 4; j++) {
                int grow = m0 + wm * 64 + m * 16 + fq * 4 + j;
                C[(size_t)grow * 256 + gcol] = f2bf(acc[m][n][j] + bv);
            }
        }
    }
}

// ======== batched-by-head GEMM: h1 = relu([agg|feat] @ [W1|resW1]_h^T + b1) ========
// K-loop split into two STATIC halves: k<256 from Acomb, k>=256 from featb.
__global__ __launch_bounds__(256) void gemm_h1(
    const short* __restrict__ Acomb, const short* __restrict__ featb,
    const short* __restrict__ Wcomb, const float* __restrict__ b1, short* __restrict__ h1b)
{
    __shared__ short sA[2][128 * 32];
    __shared__ short sB[2][128 * 32];
    const int tid  = threadIdx.x;
    const int wave = tid >> 6, lane = tid & 63;
    const int wm = wave >> 1, wn = wave & 1;
    int lid = xcd_logical_id();                  // grid (4, M/128, 4)
    const int bx = lid & 3;
    const int by = (lid >> 2) % gridDim.y;
    const int h  = lid / (gridDim.y * 4);
    const int m0 = by * 128, n0 = bx * 128;
    const short* Bt = Wcomb + (size_t)(h * 512) * 512;

    const int srow = tid >> 2;
    const int scol = (tid & 3) * 8;
    const int fr = lane & 15;
    const int fq = lane >> 4;

    f32x4 acc[4][4] = {};

    // ---- half 1: K 0..256 from Acomb [M*4, 256] ----
#pragma unroll 2
    for (int k0 = 0; k0 < 256; k0 += 64) {
#pragma unroll
        for (int hh = 0; hh < 2; hh++) {
            int kc = k0 + hh * 32 + scol;
            stage_pair(Acomb + ((size_t)(m0 + srow) * 4 + h) * 256 + kc,
                       Acomb + ((size_t)(m0 + 64 + srow) * 4 + h) * 256 + kc,
                       Bt + (size_t)(n0 + srow) * 512 + kc,
                       Bt + (size_t)(n0 + 64 + srow) * 512 + kc,
                       sA[hh], sB[hh], wave);
        }
        __syncthreads();
#pragma unroll
        for (int hh = 0; hh < 2; hh++)
            mfma_step(sA[hh], sB[hh], wm, wn, fr, fq, acc);
        __syncthreads();
    }
    // ---- half 2: K 256..512 from featb [M, 256] (residual operand) ----
#pragma unroll 2
    for (int k0 = 256; k0 < 512; k0 += 64) {
#pragma unroll
        for (int hh = 0; hh < 2; hh++) {
            int kc = k0 + hh * 32 + scol;
            stage_pair(featb + (size_t)(m0 + srow) * 256 + (kc - 256),
                       featb + (size_t)(m0 + 64 + srow) * 256 + (kc - 256),
                       Bt + (size_t)(n0 + srow) * 512 + kc,
                       Bt + (size_t)(n0 + 64 + srow) * 512 + kc,
                       sA[hh], sB[hh], wave);
        }
        __syncthreads();
#pragma unroll
        for (int hh = 0; hh < 2; hh++)
            mfma_step(sA[hh], sB[hh], wm, wn, fr, fq, acc);
        __syncthreads();
    }

#pragma unroll
    for (int n = 0; n < 4; n++) {
        int gcol = h * 512 + n0 + wn * 64 + n * 16 + fr;
        float bv = b1[gcol];
#pragma unroll
        for (int m = 0; m < 4; m++) {
#pragma unroll
            for (int j = 0; j < 4; j++) {
                int grow = m0 + wm * 64 + m * 16 + fq * 4 + j;
                float v = acc[m][n][j] + bv;
                h1b[(size_t)grow * 2048 + gcol] = f2bf(v > 0.f ? v : 0.f);
            }
        }
    }
}

// ======== final thin GEMM: out[M,40] = h2[M,512] @ Wtout^T + bout ========
__global__ __launch_bounds__(256) void gemm_final(
    const short* __restrict__ A, const short* __restrict__ Bt,
    const float* __restrict__ bias, float* __restrict__ C)
{
    __shared__ short sA[2][64 * 32];
    __shared__ short sB[2][64 * 32];
    const int tid  = threadIdx.x;
    const int wave = tid >> 6, lane = tid & 63;
    const int wm = wave >> 1, wn = wave & 1;
    int lid = xcd_logical_id();          // 1-D grid, %8==0
    const int m0 = lid * 64;

    const int srow = tid >> 2;           // 0..63
    const int scol = (tid & 3) * 8;
    const int fr = lane & 15;
    const int fq = lane >> 4;

    f32x4 acc[2][2] = {};

#pragma unroll 2
    for (int k0 = 0; k0 < 512; k0 += 64) {
#pragma unroll
        for (int hh = 0; hh < 2; hh++) {
            int kc = k0 + hh * 32 + scol;
            const short* ga = A  + (size_t)(m0 + srow) * 512 + kc;
            const short* gb = Bt + (size_t)srow * 512 + kc;      // outcols 0..63
            __builtin_amdgcn_global_load_lds((const __attribute__((address_space(1))) void*)ga,
                (__attribute__((address_space(3))) void*)(sA[hh] + wave * 512), 16, 0, 0);
            __builtin_amdgcn_global_load_lds((const __attribute__((address_space(1))) void*)gb,
                (__attribute__((address_space(3))) void*)(sB[hh] + wave * 512), 16, 0, 0);
        }
        __syncthreads();

#pragma unroll
        for (int hh = 0; hh < 2; hh++) {
            bf16x8 af[2], bfr[2];
#pragma unroll
            for (int m = 0; m < 2; m++)
                af[m] = *(const bf16x8*)(sA[hh] + (wm * 32 + m * 16 + fr) * 32 + fq * 8);
#pragma unroll
            for (int n = 0; n < 2; n++)
                bfr[n] = *(const bf16x8*)(sB[hh] + (wn * 32 + n * 16 + fr) * 32 + fq * 8);
#pragma unroll
            for (int m = 0; m < 2; m++)
#pragma unroll
                for (int n = 0; n < 2; n++)
                    acc[m][n] = __builtin_amdgcn_mfma_f32_16x16x32_bf16(af[m], bfr[n], acc[m][n], 0, 0, 0);
        }
        __syncthreads();
    }

#pragma unroll
    for (int n = 0; n < 2; n++) {
        int gcol = wn * 32 + n * 16 + fr;
        if (gcol >= 40) continue;
        float bv = bias[gcol];
#pragma unroll
        for (int m = 0; m < 2; m++) {
#pragma unroll
            for (int j = 0; j < 4; j++) {
                int grow = m0 + wm * 32 + m * 16 + fq * 4 + j;
                C[(size_t)grow * 40 + gcol] = acc[m][n][j] + bv;
            }
        }
    }
}

// ======== CSR scan + scatter ========
__global__ __launch_bounds__(1024) void scan_excl(const int* __restrict__ deg,
                                                  int* __restrict__ off, int N)
{
    __shared__ int part[1024];
    int t = threadIdx.x;
    int chunk = N >> 10;
    int base = t * chunk;
    int local[16];
    int s = 0;
    for (int i = 0; i < chunk; i++) { local[i] = s; s += deg[base + i]; }
    part[t] = s;
    __syncthreads();
    for (int o = 1; o < 1024; o <<= 1) {
        int v = (t >= o) ? part[t - o] : 0;
        __syncthreads();
        part[t] += v;
        __syncthreads();
    }
    int pre = (t == 0) ? 0 : part[t - 1];
    for (int i = 0; i < chunk; i++) off[base + i] = pre + local[i];
    if (t == 1023) off[N] = pre + s;
}

__global__ void scatter_kernel(const int* __restrict__ dst, const int* __restrict__ off,
                               int* __restrict__ cur, int* __restrict__ eid, int E)
{
    int e = blockIdx.x * blockDim.x + threadIdx.x;
    if (e < E) {
        int d = dst[e];
        int p = off[d] + atomicAdd(&cur[d], 1);
        eid[p] = e;
    }
}

// ======== L1: fused edge-softmax + feature aggregation -> slim Acomb [N*4,256] ========
// 4-way edge unroll.
__global__ __launch_bounds__(256) void aggregate_feat_sm(
    const int* __restrict__ off, const int* __restrict__ eid, const int* __restrict__ src,
    const float* __restrict__ el, const float* __restrict__ er,
    const short* __restrict__ featb, short* __restrict__ Acomb)
{
    int wv = threadIdx.x >> 6, lane = threadIdx.x & 63;
    int n = blockIdx.x * 4 + wv;
    int k4 = lane * 4;
    float4 erv = ((const float4*)er)[n];
    float acc[4][4] = {};
    float accd[4] = {};
    int beg = off[n], end = off[n + 1];
    int j = beg;
    for (; j + 3 < end; j += 4) {
        int e0 = eid[j], e1 = eid[j + 1], e2 = eid[j + 2], e3 = eid[j + 3];
        int s0 = src[e0], s1 = src[e1], s2 = src[e2], s3 = src[e3];
        float4 elv0 = ((const float4*)el)[s0];
        float4 elv1 = ((const float4*)el)[s1];
        float4 elv2 = ((const float4*)el)[s2];
        float4 elv3 = ((const float4*)el)[s3];
        short4v fv0 = *(const short4v*)(featb + (size_t)s0 * 256 + k4);
        short4v fv1 = *(const short4v*)(featb + (size_t)s1 * 256 + k4);
        short4v fv2 = *(const short4v*)(featb + (size_t)s2 * 256 + k4);
        short4v fv3 = *(const short4v*)(featb + (size_t)s3 * 256 + k4);
        float a[4][4];
        a[0][0] = elv0.x + erv.x; a[0][1] = elv0.y + erv.y; a[0][2] = elv0.z + erv.z; a[0][3] = elv0.w + erv.w;
        a[1][0] = elv1.x + erv.x; a[1][1] = elv1.y + erv.y; a[1][2] = elv1.z + erv.z; a[1][3] = elv1.w + erv.w;
        a[2][0] = elv2.x + erv.x; a[2][1] = elv2.y + erv.y; a[2][2] = elv2.z + erv.z; a[2][3] = elv2.w + erv.w;
        a[3][0] = elv3.x + erv.x; a[3][1] = elv3.y + erv.y; a[3][2] = elv3.z + erv.z; a[3][3] = elv3.w + erv.w;
#pragma unroll
        for (int u = 0; u < 4; u++)
#pragma unroll
            for (int h = 0; h < 4; h++) {
                float v = a[u][h];
                a[u][h] = __expf(v > 0.f ? v : 0.2f * v);
            }
        float f0[4] = { b2f(fv0[0]), b2f(fv0[1]), b2f(fv0[2]), b2f(fv0[3]) };
        float f1[4] = { b2f(fv1[0]), b2f(fv1[1]), b2f(fv1[2]), b2f(fv1[3]) };
        float f2[4] = { b2f(fv2[0]), b2f(fv2[1]), b2f(fv2[2]), b2f(fv2[3]) };
        float f3[4] = { b2f(fv3[0]), b2f(fv3[1]), b2f(fv3[2]), b2f(fv3[3]) };
#pragma unroll
        for (int h = 0; h < 4; h++) {
            accd[h] += (a[0][h] + a[1][h]) + (a[2][h] + a[3][h]);
#pragma unroll
            for (int kk = 0; kk < 4; kk++) {
                float t0 = fmaf(a[1][h], f1[kk], fmaf(a[0][h], f0[kk], acc[h][kk]));
                acc[h][kk] = fmaf(a[3][h], f3[kk], fmaf(a[2][h], f2[kk], t0));
            }
        }
    }
    for (; j < end; ++j) {
        int e = eid[j];
        int s = src[e];
        float4 elv = ((const float4*)el)[s];
        float a0 = elv.x + erv.x, a1 = elv.y + erv.y, a2 = elv.z + erv.z, a3 = elv.w + erv.w;
        a0 = __expf(a0 > 0.f ? a0 : 0.2f * a0);
        a1 = __expf(a1 > 0.f ? a1 : 0.2f * a1);
        a2 = __expf(a2 > 0.f ? a2 : 0.2f * a2);
        a3 = __expf(a3 > 0.f ? a3 : 0.2f * a3);
        accd[0] += a0; accd[1] += a1; accd[2] += a2; accd[3] += a3;
        short4v fv = *(const short4v*)(featb + (size_t)s * 256 + k4);
        float f0 = b2f(fv[0]), f1 = b2f(fv[1]), f2 = b2f(fv[2]), f3 = b2f(fv[3]);
        acc[0][0] = fmaf(a0, f0, acc[0][0]); acc[0][1] = fmaf(a0, f1, acc[0][1]);
        acc[0][2] = fmaf(a0, f2, acc[0][2]); acc[0][3] = fmaf(a0, f3, acc[0][3]);
        acc[1][0] = fmaf(a1, f0, acc[1][0]); acc[1][1] = fmaf(a1, f1, acc[1][1]);
        acc[1][2] = fmaf(a1, f2, acc[1][2]); acc[1][3] = fmaf(a1, f3, acc[1][3]);
        acc[2][0] = fmaf(a2, f0, acc[2][0]); acc[2][1] = fmaf(a2, f1, acc[2][1]);
        acc[2][2] = fmaf(a2, f2, acc[2][2]); acc[2][3] = fmaf(a2, f3, acc[2][3]);
        acc[3][0] = fmaf(a3, f0, acc[3][0]); acc[3][1] = fmaf(a3, f1, acc[3][1]);
        acc[3][2] = fmaf(a3, f2, acc[3][2]); acc[3][3] = fmaf(a3, f3, acc[3][3]);
    }
    float inv[4];
#pragma unroll
    for (int h = 0; h < 4; h++) inv[h] = 1.f / (accd[h] == 0.f ? 1.f : accd[h]);
#pragma unroll
    for (int h = 0; h < 4; h++) {
        short4v o;
#pragma unroll
        for (int kk = 0; kk < 4; kk++) o[kk] = f2bf(acc[h][kk] * inv[h]);
        *(short4v*)(Acomb + ((size_t)n * 4 + h) * 256 + k4) = o;
    }
}

// ======== L2: fused edge-softmax + aggregation on z2res[M=N*4,256]=[z2|res2+b2] ========
// 8-way edge unroll (mean degree 8); residual load hoisted.
__global__ __launch_bounds__(256) void aggregate2_sm(
    const int* __restrict__ off, const int* __restrict__ eid, const int* __restrict__ src,
    const float* __restrict__ el, const float* __restrict__ er,
    const short* __restrict__ z2res, short* __restrict__ h2)
{
    int n = blockIdx.x, t = threadIdx.x;
    int c = t >> 4;
    int p = t >> 6;
    int rem = (2 * t) & 127;
    float erv = er[n * 16 + c];
    unsigned rv = *(const unsigned*)(z2res + ((size_t)n * 4 + p) * 256 + 128 + rem);
    float r0 = 0.f, r1 = 0.f, dn = 0.f;
    int beg = off[n], end = off[n + 1];
    int j = beg;
    for (; j + 7 < end; j += 8) {
        int s[8];
#pragma unroll
        for (int u = 0; u < 8; u++) s[u] = src[eid[j + u]];
        float lv[8];
        unsigned zv[8];
#pragma unroll
        for (int u = 0; u < 8; u++) {
            lv[u] = el[s[u] * 16 + c] + erv;
            zv[u] = *(const unsigned*)(z2res + ((size_t)s[u] * 4 + p) * 256 + rem);
        }
#pragma unroll
        for (int u = 0; u < 8; u++) {
            float a = __expf(lv[u] > 0.f ? lv[u] : 0.2f * lv[u]);
            dn += a;
            r0 = fmaf(a, b2f((short)(zv[u] & 0xFFFFu)), r0);
            r1 = fmaf(a, b2f((short)(zv[u] >> 16)), r1);
        }
    }
    for (; j < end; ++j) {
        int s = src[eid[j]];
        float lv = el[s * 16 + c] + erv;
        float a = __expf(lv > 0.f ? lv : 0.2f * lv);
        dn += a;
        unsigned zv = *(const unsigned*)(z2res + ((size_t)s * 4 + p) * 256 + rem);
        r0 = fmaf(a, b2f((short)(zv & 0xFFFFu)), r0);
        r1 = fmaf(a, b2f((short)(zv >> 16)), r1);
    }
    if (dn == 0.f) dn = 1.f;
    float inv = 1.f / dn;
    float v0 = r0 * inv + b2f((short)(rv & 0xFFFFu));
    float v1 = r1 * inv + b2f((short)(rv >> 16));
    v0 = v0 > 0.f ? v0 : 0.f;
    v1 = v1 > 0.f ? v1 : 0.f;
    unsigned o = ((unsigned)(unsigned short)f2bf(v1) << 16) | (unsigned)(unsigned short)f2bf(v0);
    *(unsigned*)(h2 + (size_t)n * 512 + t * 2) = o;
}

// ======== launch ========
extern "C" void kernel_launch(void* const* d_in, const int* in_sizes, int n_in,
                              void* d_out, int out_size, void* d_ws, size_t ws_size,
                              hipStream_t stream)
{
    const float* feat  = (const float*)d_in[0];
    const int*   src   = (const int*)d_in[1];
    const int*   dst   = (const int*)d_in[2];
    const float* W1    = (const float*)d_in[3];
    const float* al1   = (const float*)d_in[4];
    const float* ar1   = (const float*)d_in[5];
    const float* resW1 = (const float*)d_in[6];
    const float* b1    = (const float*)d_in[7];
    const float* W2    = (const float*)d_in[8];
    const float* al2   = (const float*)d_in[9];
    const float* ar2   = (const float*)d_in[10];
    const float* resW2 = (const float*)d_in[11];
    const float* b2    = (const float*)d_in[12];
    const float* Wout  = (const float*)d_in[13];
    const float* bout  = (const float*)d_in[14];
    const int N = in_sizes[0] / IN_F;  // 8192
    const int E = in_sizes[1];         // 65536

    // ---- workspace layout (~80 MB) ----
    char* w = (char*)d_ws;
    auto alloc = [&](size_t bytes) -> char* {
        char* p = w;
        w += (bytes + 255) & ~(size_t)255;
        return p;
    };
    short*    Acomb   = (short*)alloc((size_t)N * 4 * 256 * 2);   // 16 MB (slim)
    short*    h1b     = (short*)alloc((size_t)N * 2048 * 2);      // 32 MB
    short*    featb   = (short*)alloc((size_t)N * 256 * 2);       // 4 MB
    short*    Wcomb   = (short*)alloc((size_t)2048 * 512 * 2);    // 2 MB
    short*    W2comb  = (short*)alloc((size_t)256 * 512 * 2);
    short*    Wtout   = (short*)alloc((size_t)128 * 512 * 2);
    float*    bias2c  = (float*)alloc((size_t)256 * 4);
    float*    wal1    = (float*)alloc((size_t)256 * 4 * 4);
    float*    war1    = (float*)alloc((size_t)256 * 4 * 4);
    float*    el1     = (float*)alloc((size_t)N * 4 * 4);
    float*    er1     = (float*)alloc((size_t)N * 4 * 4);
    int*      deg     = (int*)alloc((size_t)N * 4);               // deg+cur contiguous:
    int*      cur     = (int*)alloc((size_t)N * 4);               //   prep_all zeroes both
    int*      off     = (int*)alloc((size_t)(N + 1) * 4);
    int*      eid     = (int*)alloc((size_t)E * 4);
    short*    z2res   = (short*)alloc((size_t)N * 4 * 256 * 2);   // 16 MB
    short*    h2b     = (short*)alloc((size_t)N * 512 * 2);       // 8 MB
    float*    el2     = (float*)alloc((size_t)N * 16 * 4);
    float*    er2     = (float*)alloc((size_t)N * 16 * 4);

    dim3 blk(256);

    // ===== prep: fold1 + weight cvt + bias2c + zero(deg,cur) =====
    prep_all<<<dim3(1489), blk, 0, stream>>>(W1, al1, ar1, resW1, resW2, W2, Wout, b2,
                                             Wcomb, W2comb, Wtout,
                                             wal1, war1, bias2c, deg);

    // ===== front: feat cvt + el1/er1 + dst histogram (one dispatch) =====
    l1_front<<<dim3(N / 4 + E / 256), blk, 0, stream>>>(feat, (const float4*)wal1, (const float4*)war1,
                                                        featb, el1, er1, dst, deg, E, N / 4);
    scan_excl<<<dim3(1), dim3(1024), 0, stream>>>(deg, off, N);
    scatter_kernel<<<dim3((E + 255) / 256), blk, 0, stream>>>(dst, off, cur, eid, E);

    // ===== layer 1 =====
    aggregate_feat_sm<<<dim3(N / 4), blk, 0, stream>>>(off, eid, src, el1, er1, featb, Acomb);
    gemm_h1<<<dim3(4, N / 128, 4), blk, 0, stream>>>(Acomb, featb, Wcomb, b1, h1b);
    // h1b = bf16 h1 [N,4,512]

    // ===== layer 2 (specialized GEMM with fused el2/er2 epilogue) =====
    gemm_l2<<<dim3(2, (N * 4) / 128), blk, 0, stream>>>(h1b, W2comb, bias2c, z2res,
                                                        el2, er2, al2, ar2);
    aggregate2_sm<<<dim3(N), blk, 0, stream>>>(off, eid, src, el2, er2, z2res, h2b);
    // h2b = bf16 h2 [N,512]

    // ===== final linear (64x64 tile, 128 blocks) =====
    gemm_final<<<dim3(N / 64), blk, 0, stream>>>(h2b, Wtout, bout, (float*)d_out);
}